// Round 6
// baseline (416.769 us; speedup 1.0000x reference)
//
#include <hip/hip_runtime.h>
#include <stdint.h>

typedef unsigned short u16;
typedef __attribute__((ext_vector_type(8))) short  s8b;   // 8 bf16 (4 VGPRs)
typedef __attribute__((ext_vector_type(4))) float  f32x4;

#define S_LEN   2048
#define NHEAD   16
#define HD      128
#define DM      2048
#define NB      2
#define NPLANE  (NB*NHEAD)          // 32
#define ROWS    (NB*S_LEN)          // 4096 = M for all GEMMs
#define PLANE_ELEMS (S_LEN*HD)      // 262144
#define ATT_SCALE 0.08838834764831845f   // 1/sqrt(128)
#define LOG2E     1.4426950408889634f

__device__ __forceinline__ float bf2f(u16 u){
  union { unsigned u; float f; } x; x.u = ((unsigned)u) << 16; return x.f;
}
__device__ __forceinline__ u16 f2bf(float f){
  union { float f; unsigned u; } x; x.f = f;
  unsigned r = x.u + 0x7FFFu + ((x.u >> 16) & 1u);   // RNE
  return (u16)(r >> 16);
}
__device__ __forceinline__ unsigned cvtpk(float lo, float hi){
  unsigned r;
  asm("v_cvt_pk_bf16_f32 %0, %1, %2" : "=v"(r) : "v"(lo), "v"(hi));
  return r;
}

typedef const __attribute__((address_space(1))) unsigned int* gas1;
typedef __attribute__((address_space(3))) unsigned int* las3;
__device__ __forceinline__ void gload16(const void* g, void* l){
  // async global->LDS, dest = wave-uniform base + lane*16
  __builtin_amdgcn_global_load_lds((gas1)g, (las3)l, 16, 0, 0);
}

__device__ __forceinline__ f32x4 mfma16(s8b a, s8b b, f32x4 c){
  return __builtin_amdgcn_mfma_f32_16x16x32_bf16(a, b, c, 0, 0, 0);
}

// ---------------- elementwise f32 -> bf16, 3 tensors in one launch ----------------
__global__ __launch_bounds__(256) void cvt4x3(const float4* __restrict__ a,
                                              const float4* __restrict__ b,
                                              const float4* __restrict__ c,
                                              uint2* __restrict__ oa,
                                              uint2* __restrict__ ob,
                                              uint2* __restrict__ oc, int n4){
  int i = blockIdx.x*256 + threadIdx.x;
  if (i >= n4) return;
  const float4* src = (blockIdx.y == 0) ? a : (blockIdx.y == 1) ? b : c;
  uint2*       dst  = (blockIdx.y == 0) ? oa : (blockIdx.y == 1) ? ob : oc;
  float4 v = src[i];
  uint2 o;
  o.x = (unsigned)f2bf(v.x) | ((unsigned)f2bf(v.y) << 16);
  o.y = (unsigned)f2bf(v.z) | ((unsigned)f2bf(v.w) << 16);
  dst[i] = o;
}

// ---------------- tiled transpose + convert: in[z][R][C] f32 -> out[z][C][outStride] bf16 ----
__global__ __launch_bounds__(256) void transpose_cvt(const float* __restrict__ in,
                                                     u16* __restrict__ out,
                                                     int R, int C, int outStride){
  __shared__ float tile[32][33];
  int z = blockIdx.z;
  const float* inz = in + (size_t)z * R * C;
  u16* outz = out + (size_t)z * C * outStride;
  int r0 = blockIdx.x*32, c0 = blockIdx.y*32;
  int tx = threadIdx.x, ty = threadIdx.y;   // (32,8)
  #pragma unroll
  for (int i=0;i<4;i++)
    tile[ty*4+i][tx] = inz[(size_t)(r0+ty*4+i)*C + c0 + tx];
  __syncthreads();
  #pragma unroll
  for (int i=0;i<4;i++)
    outz[(size_t)(c0+ty*4+i)*outStride + r0 + tx] = f2bf(tile[tx][ty*4+i]);
}

// ---------------- RoPE table (f32, matches reference f32 computation) ----------------
__global__ __launch_bounds__(256) void rope_tab(float* __restrict__ ctab,
                                                float* __restrict__ stab){
  int i = blockIdx.x*256 + threadIdx.x;   // S_LEN*64
  int p = i >> 6, j = i & 63;
  // freq = 10000^(-j/64) = exp2(-j * log2(10000)/64)
  float freq = exp2f(-(float)j * (13.287712379549449f/64.0f));
  float a = (float)p * freq;
  ctab[i] = cosf(a);
  stab[i] = sinf(a);
}

// ---------------- GEMM: A[4096][2048] bf16 x BT[2048][2048] bf16 (B^T layout) ------------
// 128^2 tile, 4 waves, 16KB dbuf LDS, XCD swizzle, kt-unroll x2 (compile-time cur). grid 1D 512.
// mode 0: out bf16 plain (B,H,S,F)      (q_raw / k_raw)
// mode 1: out bf16 V^T tiled+swizzled+pi-permuted (per plane, tiles of [128 f][64 p])
// mode 2: out f32 [4096][2048] + bias   (final output)
__global__ __launch_bounds__(256) void gemm_bt(const u16* __restrict__ A,
                                               const u16* __restrict__ BT,
                                               const float* __restrict__ bias,
                                               void* __restrict__ out, int mode){
  const int K = 2048;
  __shared__ u16 As[2][4096];   // [128 m][32 k]
  __shared__ u16 Bs[2][4096];   // [128 n][32 k]
  const int t = threadIdx.x, w = t >> 6, l = t & 63;
  const int lr = l & 15, lg = l >> 4;
  // XCD-aware bijective swizzle (512 % 8 == 0)
  int bid = blockIdx.x;
  int swz = (bid & 7)*64 + (bid >> 3);
  const int M0 = (swz >> 4) * 128, N0 = (swz & 15) * 128;
  const int wr = w >> 1, wc = w & 1;     // wave 64x64 quadrant

  f32x4 acc[4][4];
  #pragma unroll
  for (int i=0;i<4;i++)
    #pragma unroll
    for (int j=0;j<4;j++) acc[i][j] = f32x4{0.f,0.f,0.f,0.f};

  auto stage = [&](int buf, int kt){
    #pragma unroll
    for (int c=0;c<2;c++){
      int mloc = c*64 + w*16 + (l>>2);
      int kloc = (l&3)*8;
      gload16(A  + (size_t)(M0+mloc)*K + kt*32 + kloc, &As[buf][c*2048 + w*512]);
      gload16(BT + (size_t)(N0+mloc)*K + kt*32 + kloc, &Bs[buf][c*2048 + w*512]);
    }
  };

#define GBODY(CUR) { \
    s8b af[4], bf[4]; \
    _Pragma("unroll") \
    for (int i=0;i<4;i++){ \
      af[i] = *(const s8b*)&As[CUR][(wr*64 + i*16 + lr)*32 + lg*8]; \
      bf[i] = *(const s8b*)&Bs[CUR][(wc*64 + i*16 + lr)*32 + lg*8]; \
    } \
    __builtin_amdgcn_s_setprio(1); \
    _Pragma("unroll") \
    for (int i=0;i<4;i++) \
      _Pragma("unroll") \
      for (int j=0;j<4;j++) \
        acc[i][j] = mfma16(af[i], bf[j], acc[i][j]); \
    __builtin_amdgcn_s_setprio(0); \
  }

  stage(0, 0);
  const int NT = K/32;                     // 64 (even)
  for (int kt2=0; kt2<NT/2; kt2++){
    int kt = kt2*2;
    __syncthreads();                       // buf0 staged; prev buf1 reads done
    stage(1, kt+1);
    GBODY(0);
    __syncthreads();                       // buf1 staged; buf0 reads done
    if (kt+2 < NT) stage(0, kt+2);
    GBODY(1);
  }
#undef GBODY

  // epilogue: D layout col=lane&15, row=(lane>>4)*4+reg
  #pragma unroll
  for (int i=0;i<4;i++){
    int growb = M0 + wr*64 + i*16 + lg*4;
    #pragma unroll
    for (int j=0;j<4;j++){
      int gcol = N0 + wc*64 + j*16 + lr;
      float bv = bias[gcol];
      #pragma unroll
      for (int r=0;r<4;r++){
        int grow = growb + r;
        float v = acc[i][j][r] + bv;
        if (mode == 2){
          ((float*)out)[(size_t)grow*2048 + gcol] = v;
        } else {
          int b = grow >> 11, p = grow & 2047;
          int h = gcol >> 7,  f = gcol & 127;
          if (mode == 0){
            ((u16*)out)[(((size_t)(b*NHEAD+h))*S_LEN + p)*HD + f] = f2bf(v);
          } else {
            // V^T tile: pi-permute kv within 32 so PV B-frag matches in-reg P sigma order
            size_t base = ((size_t)(b*NHEAD+h)*PLANE_ELEMS + (size_t)(p>>6)*8192) * 2;
            int p6 = p & 63;
            int q_ = ((p6&12)<<1) | (p6&3) | ((p6&16)>>2);
            int kvp = (p6 & 32) | q_;
            int byte = (f*128 + kvp*2) ^ ((f&7)<<4);
            *(u16*)((char*)out + base + byte) = f2bf(v);
          }
        }
      }
    }
  }
}

// ---------------- RMSNorm + RoPE: one wave per row of 128 ----------------
// swizzled=0: write plain (B,H,S,F), scaled by oscale. swizzled=1: write K tiled+swizzled
__global__ __launch_bounds__(256) void norm_rope(const u16* __restrict__ in,
                                                 u16* __restrict__ outp,
                                                 const float* __restrict__ nw,
                                                 const float* __restrict__ ctab,
                                                 const float* __restrict__ stab,
                                                 int swizzled, float oscale){
  int t = threadIdx.x, w = t>>6, l = t&63;
  size_t R = (size_t)blockIdx.x*4 + w;     // over B*H*S rows
  int p = (int)(R & (S_LEN-1));
  size_t base = R * HD;
  float x0 = bf2f(in[base + l]);
  float x1 = bf2f(in[base + 64 + l]);
  float ss = x0*x0 + x1*x1;
  #pragma unroll
  for (int m=1;m<64;m<<=1) ss += __shfl_xor(ss, m);
  float rms = sqrtf(ss * (1.0f/128.0f));
  float sc = oscale / (rms + 1e-6f);
  float xn0 = x0 * sc * nw[l];
  float xn1 = x1 * sc * nw[64+l];
  float c = ctab[(size_t)p*64 + l], s = stab[(size_t)p*64 + l];
  float o0 = xn0*c - xn1*s;
  float o1 = xn1*c + xn0*s;
  if (!swizzled){
    outp[base + l]      = f2bf(o0);
    outp[base + 64 + l] = f2bf(o1);
  } else {
    size_t plane = R >> 11;
    int kv = p & 63;
    size_t tb = (plane*(size_t)PLANE_ELEMS + (size_t)(p>>6)*8192) * 2;
    int b0 = (kv*256 + l*2)        ^ ((kv&7)<<4);
    int b1 = (kv*256 + (64+l)*2)   ^ ((kv&7)<<4);
    *(u16*)((char*)outp + tb + b0) = f2bf(o0);
    *(u16*)((char*)outp + tb + b1) = f2bf(o1);
  }
}

// ---------------- flash attention: 8 waves, QBLK=128 (16 rows/wave), KVBLK=64 ----------------
// swapped QK^T -> P in-register; log2 softmax; cvt_pk; defer-max; kt-unroll x2; XCD-pinned
__global__ __launch_bounds__(512) void attn_fwd(const u16* __restrict__ qn,   // plain BHSF (prescaled by ATT_SCALE*LOG2E)
                                                const u16* __restrict__ kn,   // tiled swizzled
                                                const u16* __restrict__ vt,   // V^T tiled swizzled+permuted
                                                u16* __restrict__ attn_out){  // (B,S,H,F)
  __shared__ u16 Klds[2][8192];     // [64 kv][128 f] swizzled
  __shared__ u16 Vlds[2][8192];     // [128 f][64 kv] swizzled+permuted
  int t = threadIdx.x, w = t>>6, l = t&63;
  int lr = l&15, lg = l>>4;

  // XCD-aware decomposition: plane pinned to one XCD (bid&7); 512 blocks
  int bid = blockIdx.x;                  // 0..511
  int xcd = bid & 7, j = bid >> 3;       // j 0..63
  int plane = xcd*4 + (j >> 4);          // 4 planes per XCD
  int qb = j & 15;
  int q0 = qb*128 + w*16;

  s8b qf[4];
  #pragma unroll
  for (int fc=0; fc<4; fc++)
    qf[fc] = *(const s8b*)(qn + ((size_t)plane*S_LEN + q0 + lr)*HD + fc*32 + lg*8);

  float m = -1e30f, lsum = 0.f;          // per-lane (q = q0+lr); log2-domain max
  f32x4 oacc[8];
  #pragma unroll
  for (int i=0;i<8;i++) oacc[i] = f32x4{0.f,0.f,0.f,0.f};

  const u16* kbase = kn + (size_t)plane*PLANE_ELEMS;
  const u16* vbase = vt + (size_t)plane*PLANE_ELEMS;

  auto stage = [&](int buf, int kt){
    #pragma unroll
    for (int i=0;i<2;i++){
      gload16(kbase + (size_t)kt*8192 + w*1024 + i*512 + l*8, &Klds[buf][w*1024 + i*512]);
      gload16(vbase + (size_t)kt*8192 + w*1024 + i*512 + l*8, &Vlds[buf][w*1024 + i*512]);
    }
  };

#define ATILE(CUR) { \
    f32x4 sacc[4]; \
    _Pragma("unroll") \
    for (int c=0;c<4;c++) sacc[c] = f32x4{0.f,0.f,0.f,0.f}; \
    __builtin_amdgcn_s_setprio(1); \
    _Pragma("unroll") \
    for (int c=0;c<4;c++){ \
      int kv = c*16 + lr; \
      _Pragma("unroll") \
      for (int fc=0; fc<4; fc++){ \
        int byte = (kv*256 + (fc*32 + lg*8)*2) ^ ((kv&7)<<4); \
        s8b kf = *(const s8b*)((const char*)&Klds[CUR][0] + byte); \
        sacc[c] = mfma16(kf, qf[fc], sacc[c]); \
      } \
    } \
    __builtin_amdgcn_s_setprio(0); \
    float mx01 = fmaxf(fmaxf(sacc[0][0], sacc[0][1]), fmaxf(sacc[0][2], sacc[0][3])); \
    float mx11 = fmaxf(fmaxf(sacc[1][0], sacc[1][1]), fmaxf(sacc[1][2], sacc[1][3])); \
    float mx21 = fmaxf(fmaxf(sacc[2][0], sacc[2][1]), fmaxf(sacc[2][2], sacc[2][3])); \
    float mx31 = fmaxf(fmaxf(sacc[3][0], sacc[3][1]), fmaxf(sacc[3][2], sacc[3][3])); \
    float mx = fmaxf(fmaxf(mx01, mx11), fmaxf(mx21, mx31)); \
    if (__any(mx > m + 11.5f)){ \
      float v = mx; \
      v = fmaxf(v, __shfl_xor(v, 16)); \
      v = fmaxf(v, __shfl_xor(v, 32)); \
      v = fmaxf(m, v); \
      float al = exp2f(m - v); \
      m = v; lsum *= al; \
      float alr[4]; \
      _Pragma("unroll") \
      for (int r=0;r<4;r++) alr[r] = __shfl(al, lg*4 + r); \
      _Pragma("unroll") \
      for (int i=0;i<8;i++) \
        _Pragma("unroll") \
        for (int r=0;r<4;r++) oacc[i][r] *= alr[r]; \
    } \
    float pv[4][4]; \
    float ls0 = 0.f, ls1 = 0.f, ls2 = 0.f, ls3 = 0.f; \
    _Pragma("unroll") \
    for (int c=0;c<4;c++){ \
      float e0 = exp2f(sacc[c][0] - m); \
      float e1 = exp2f(sacc[c][1] - m); \
      float e2 = exp2f(sacc[c][2] - m); \
      float e3 = exp2f(sacc[c][3] - m); \
      pv[c][0]=e0; pv[c][1]=e1; pv[c][2]=e2; pv[c][3]=e3; \
      ls0 += e0; ls1 += e1; ls2 += e2; ls3 += e3; \
    } \
    lsum += (ls0 + ls1) + (ls2 + ls3); \
    s8b pa[2]; \
    _Pragma("unroll") \
    for (int kc=0;kc<2;kc++){ \
      union { s8b v; unsigned u[4]; } pu; \
      pu.u[0] = cvtpk(pv[2*kc][0],   pv[2*kc][1]); \
      pu.u[1] = cvtpk(pv[2*kc][2],   pv[2*kc][3]); \
      pu.u[2] = cvtpk(pv[2*kc+1][0], pv[2*kc+1][1]); \
      pu.u[3] = cvtpk(pv[2*kc+1][2], pv[2*kc+1][3]); \
      pa[kc] = pu.v; \
    } \
    __builtin_amdgcn_s_setprio(1); \
    _Pragma("unroll") \
    for (int kc=0;kc<2;kc++){ \
      _Pragma("unroll") \
      for (int fc2=0; fc2<8; fc2++){ \
        int f = fc2*16 + lr; \
        int byte = (f*128 + (kc*32 + lg*8)*2) ^ ((f&7)<<4); \
        s8b vf = *(const s8b*)((const char*)&Vlds[CUR][0] + byte); \
        oacc[fc2] = mfma16(pa[kc], vf, oacc[fc2]); \
      } \
    } \
    __builtin_amdgcn_s_setprio(0); \
  }

  stage(0, 0);
  for (int kt2=0; kt2<16; kt2++){
    int kt = kt2*2;
    __syncthreads();                    // buf0 staged; buf1 reads done
    stage(1, kt+1);
    ATILE(0);
    __syncthreads();                    // buf1 staged; buf0 reads done
    if (kt+2 < 32) stage(0, kt+2);
    ATILE(1);
  }
#undef ATILE

  // final: reduce lsum across the 4 lane-groups (q=lr), redistribute to q=lg*4+r
  {
    float v = lsum;
    v += __shfl_xor(v, 16);
    v += __shfl_xor(v, 32);
    lsum = 1.0f / v;
  }
  float lir[4];
  #pragma unroll
  for (int r=0;r<4;r++) lir[r] = __shfl(lsum, lg*4 + r);
  int b = plane >> 4, h = plane & 15;
  #pragma unroll
  for (int fc2=0; fc2<8; fc2++){
    int f = fc2*16 + lr;
    #pragma unroll
    for (int r=0;r<4;r++){
      int row = q0 + lg*4 + r;
      float v = oacc[fc2][r] * lir[r];
      attn_out[(((size_t)b*S_LEN + row)*NHEAD + h)*HD + f] = f2bf(v);
    }
  }
}

// ---------------------------------------------------------------------------
extern "C" void kernel_launch(void* const* d_in, const int* in_sizes, int n_in,
                              void* d_out, int out_size, void* d_ws, size_t ws_size,
                              hipStream_t stream){
  const float* xq = (const float*)d_in[0];
  const float* xk = (const float*)d_in[1];
  const float* xv = (const float*)d_in[2];
  const float* WQ = (const float*)d_in[3];
  const float* WK = (const float*)d_in[4];
  const float* WV = (const float*)d_in[5];
  const float* WO = (const float*)d_in[6];
  const float* bQ = (const float*)d_in[7];
  const float* bK = (const float*)d_in[8];
  const float* bV = (const float*)d_in[9];
  const float* bO = (const float*)d_in[10];
  const float* qw = (const float*)d_in[11];
  const float* kw = (const float*)d_in[12];

  char* ws = (char*)d_ws;
  size_t off = 0;
  auto alloc = [&](size_t bytes)->void*{
    void* p = ws + off; off += (bytes + 255) & ~(size_t)255; return p;
  };
  const size_t ACT = (size_t)ROWS*DM*2;    // 16.78 MB (bf16 [4096][2048])
  const size_t WMT = (size_t)DM*DM*2;      // 8.39 MB
  u16* xqb  = (u16*)alloc(ACT);
  u16* xkb  = (u16*)alloc(ACT);
  u16* xvb  = (u16*)alloc(ACT);
  u16* WqT  = (u16*)alloc(WMT);
  u16* WkT  = (u16*)alloc(WMT);
  u16* WvT  = (u16*)alloc(WMT);
  u16* WoT  = (u16*)alloc(WMT);
  u16* qraw = (u16*)alloc(ACT);
  u16* kraw = (u16*)alloc(ACT);
  u16* knT  = (u16*)alloc(ACT);
  u16* vtS  = (u16*)alloc(ACT);
  u16* attn = (u16*)alloc(ACT);
  float* ctab = (float*)alloc((size_t)S_LEN*64*4);
  float* stab = (float*)alloc((size_t)S_LEN*64*4);
  if (off > ws_size) return;               // ws too small -> absmax will flag it

  const int n4 = ROWS*DM/4;                // 2097152
  cvt4x3<<<dim3(n4/256, 3), dim3(256), 0, stream>>>((const float4*)xq, (const float4*)xk,
                                                    (const float4*)xv, (uint2*)xqb,
                                                    (uint2*)xkb, (uint2*)xvb, n4);
  rope_tab<<<dim3(S_LEN*64/256), dim3(256), 0, stream>>>(ctab, stab);
  // W_Q/K/V: (H,D,F) -> [h*128+f][d]
  transpose_cvt<<<dim3(64,4,16), dim3(32,8), 0, stream>>>(WQ, WqT, 2048, 128, 2048);
  transpose_cvt<<<dim3(64,4,16), dim3(32,8), 0, stream>>>(WK, WkT, 2048, 128, 2048);
  transpose_cvt<<<dim3(64,4,16), dim3(32,8), 0, stream>>>(WV, WvT, 2048, 128, 2048);
  // W_O: [hf][m] -> [m][hf]
  transpose_cvt<<<dim3(64,64,1), dim3(32,8), 0, stream>>>(WO, WoT, 2048, 2048, 2048);

  gemm_bt<<<dim3(512), dim3(256), 0, stream>>>(xqb, WqT, bQ, qraw, 0);
  gemm_bt<<<dim3(512), dim3(256), 0, stream>>>(xkb, WkT, bK, kraw, 0);
  gemm_bt<<<dim3(512), dim3(256), 0, stream>>>(xvb, WvT, bV, vtS, 1);

  norm_rope<<<dim3(NPLANE*S_LEN/4), dim3(256), 0, stream>>>(qraw, qraw, qw, ctab, stab, 0, ATT_SCALE*LOG2E);
  norm_rope<<<dim3(NPLANE*S_LEN/4), dim3(256), 0, stream>>>(kraw, knT, kw, ctab, stab, 1, 1.0f);

  attn_fwd<<<dim3(512), dim3(512), 0, stream>>>(qraw, knT, vtS, attn);

  gemm_bt<<<dim3(512), dim3(256), 0, stream>>>(attn, WoT, bO, d_out, 2);
}

// Round 7
// 375.742 us; speedup vs baseline: 1.1092x; 1.1092x over previous
//
#include <hip/hip_runtime.h>
#include <stdint.h>

typedef unsigned short u16;
typedef __attribute__((ext_vector_type(8))) short  s8b;   // 8 bf16 (4 VGPRs)
typedef __attribute__((ext_vector_type(4))) float  f32x4;

#define S_LEN   2048
#define NHEAD   16
#define HD      128
#define DM      2048
#define NB      2
#define NPLANE  (NB*NHEAD)          // 32
#define ROWS    (NB*S_LEN)          // 4096 = M for all GEMMs
#define PLANE_ELEMS (S_LEN*HD)      // 262144
#define ATT_SCALE 0.08838834764831845f   // 1/sqrt(128)
#define LOG2E     1.4426950408889634f

__device__ __forceinline__ float bf2f(u16 u){
  union { unsigned u; float f; } x; x.u = ((unsigned)u) << 16; return x.f;
}
__device__ __forceinline__ u16 f2bf(float f){
  union { float f; unsigned u; } x; x.f = f;
  unsigned r = x.u + 0x7FFFu + ((x.u >> 16) & 1u);   // RNE
  return (u16)(r >> 16);
}
__device__ __forceinline__ unsigned cvtpk(float lo, float hi){
  unsigned r;
  asm("v_cvt_pk_bf16_f32 %0, %1, %2" : "=v"(r) : "v"(lo), "v"(hi));
  return r;
}

typedef const __attribute__((address_space(1))) unsigned int* gas1;
typedef __attribute__((address_space(3))) unsigned int* las3;
__device__ __forceinline__ void gload16(const void* g, void* l){
  // async global->LDS, dest = wave-uniform base + lane*16
  __builtin_amdgcn_global_load_lds((gas1)g, (las3)l, 16, 0, 0);
}

__device__ __forceinline__ f32x4 mfma16(s8b a, s8b b, f32x4 c){
  return __builtin_amdgcn_mfma_f32_16x16x32_bf16(a, b, c, 0, 0, 0);
}

// ---------------- elementwise f32 -> bf16, 3 tensors in one launch ----------------
__global__ __launch_bounds__(256) void cvt4x3(const float4* __restrict__ a,
                                              const float4* __restrict__ b,
                                              const float4* __restrict__ c,
                                              uint2* __restrict__ oa,
                                              uint2* __restrict__ ob,
                                              uint2* __restrict__ oc, int n4){
  int i = blockIdx.x*256 + threadIdx.x;
  if (i >= n4) return;
  const float4* src = (blockIdx.y == 0) ? a : (blockIdx.y == 1) ? b : c;
  uint2*       dst  = (blockIdx.y == 0) ? oa : (blockIdx.y == 1) ? ob : oc;
  float4 v = src[i];
  uint2 o;
  o.x = (unsigned)f2bf(v.x) | ((unsigned)f2bf(v.y) << 16);
  o.y = (unsigned)f2bf(v.z) | ((unsigned)f2bf(v.w) << 16);
  dst[i] = o;
}

// ---------------- tiled transpose + convert: in[z][R][C] f32 -> out[z][C][outStride] bf16 ----
__global__ __launch_bounds__(256) void transpose_cvt(const float* __restrict__ in,
                                                     u16* __restrict__ out,
                                                     int R, int C, int outStride){
  __shared__ float tile[32][33];
  int z = blockIdx.z;
  const float* inz = in + (size_t)z * R * C;
  u16* outz = out + (size_t)z * C * outStride;
  int r0 = blockIdx.x*32, c0 = blockIdx.y*32;
  int tx = threadIdx.x, ty = threadIdx.y;   // (32,8)
  #pragma unroll
  for (int i=0;i<4;i++)
    tile[ty*4+i][tx] = inz[(size_t)(r0+ty*4+i)*C + c0 + tx];
  __syncthreads();
  #pragma unroll
  for (int i=0;i<4;i++)
    outz[(size_t)(c0+ty*4+i)*outStride + r0 + tx] = f2bf(tile[tx][ty*4+i]);
}

// ---------------- RoPE table (f32) ----------------
__global__ __launch_bounds__(256) void rope_tab(float* __restrict__ ctab,
                                                float* __restrict__ stab){
  int i = blockIdx.x*256 + threadIdx.x;   // S_LEN*64
  int p = i >> 6, j = i & 63;
  float freq = exp2f(-(float)j * (13.287712379549449f/64.0f));  // 10000^(-j/64)
  float a = (float)p * freq;
  ctab[i] = cosf(a);
  stab[i] = sinf(a);
}

// ---------------- GEMM: A[4096][2048] bf16 x BT[2048][2048] bf16 (B^T layout) ------------
// round-5 proven structure: 128^2 tile, 4 waves, 16KB dbuf LDS, XCD swizzle. grid 1D 512.
// mode 0: out bf16 plain (B,H,S,F)      (q_raw / k_raw)
// mode 1: out bf16 V^T tiled+swizzled+pi-permuted (per plane, tiles of [128 f][64 p])
// mode 2: out f32 [4096][2048] + bias   (final output)
__global__ __launch_bounds__(256) void gemm_bt(const u16* __restrict__ A,
                                               const u16* __restrict__ BT,
                                               const float* __restrict__ bias,
                                               void* __restrict__ out, int mode){
  const int K = 2048;
  __shared__ u16 As[2][4096];   // [128 m][32 k]
  __shared__ u16 Bs[2][4096];   // [128 n][32 k]
  const int t = threadIdx.x, w = t >> 6, l = t & 63;
  const int lr = l & 15, lg = l >> 4;
  // XCD-aware bijective swizzle (512 % 8 == 0)
  int bid = blockIdx.x;
  int swz = (bid & 7)*64 + (bid >> 3);
  const int M0 = (swz >> 4) * 128, N0 = (swz & 15) * 128;
  const int wr = w >> 1, wc = w & 1;     // wave 64x64 quadrant

  f32x4 acc[4][4];
  #pragma unroll
  for (int i=0;i<4;i++)
    #pragma unroll
    for (int j=0;j<4;j++) acc[i][j] = f32x4{0.f,0.f,0.f,0.f};

  auto stage = [&](int buf, int kt){
    #pragma unroll
    for (int c=0;c<2;c++){
      int mloc = c*64 + w*16 + (l>>2);
      int kloc = (l&3)*8;
      gload16(A  + (size_t)(M0+mloc)*K + kt*32 + kloc, &As[buf][c*2048 + w*512]);
      gload16(BT + (size_t)(N0+mloc)*K + kt*32 + kloc, &Bs[buf][c*2048 + w*512]);
    }
  };

  stage(0, 0);
  int cur = 0;
  const int NT = K/32;
  for (int kt=0; kt<NT; kt++){
    __syncthreads();                       // staging of cur complete; prev reads drained
    if (kt+1 < NT) stage(cur^1, kt+1);
    s8b af[4], bf[4];
    #pragma unroll
    for (int i=0;i<4;i++){
      af[i] = *(const s8b*)&As[cur][(wr*64 + i*16 + lr)*32 + lg*8];
      bf[i] = *(const s8b*)&Bs[cur][(wc*64 + i*16 + lr)*32 + lg*8];
    }
    __builtin_amdgcn_s_setprio(1);
    #pragma unroll
    for (int i=0;i<4;i++)
      #pragma unroll
      for (int j=0;j<4;j++)
        acc[i][j] = mfma16(af[i], bf[j], acc[i][j]);
    __builtin_amdgcn_s_setprio(0);
    cur ^= 1;
  }

  // epilogue: D layout col=lane&15, row=(lane>>4)*4+reg
  #pragma unroll
  for (int i=0;i<4;i++){
    int growb = M0 + wr*64 + i*16 + lg*4;
    #pragma unroll
    for (int j=0;j<4;j++){
      int gcol = N0 + wc*64 + j*16 + lr;
      float bv = bias[gcol];
      #pragma unroll
      for (int r=0;r<4;r++){
        int grow = growb + r;
        float v = acc[i][j][r] + bv;
        if (mode == 2){
          ((float*)out)[(size_t)grow*2048 + gcol] = v;
        } else {
          int b = grow >> 11, p = grow & 2047;
          int h = gcol >> 7,  f = gcol & 127;
          if (mode == 0){
            ((u16*)out)[(((size_t)(b*NHEAD+h))*S_LEN + p)*HD + f] = f2bf(v);
          } else {
            // V^T tile: pi-permute kv within 32 so PV B-frag matches in-reg P sigma order
            size_t base = ((size_t)(b*NHEAD+h)*PLANE_ELEMS + (size_t)(p>>6)*8192) * 2;
            int p6 = p & 63;
            int q_ = ((p6&12)<<1) | (p6&3) | ((p6&16)>>2);
            int kvp = (p6 & 32) | q_;
            int byte = (f*128 + kvp*2) ^ ((f&7)<<4);
            *(u16*)((char*)out + base + byte) = f2bf(v);
          }
        }
      }
    }
  }
}

// ---------------- RMSNorm + RoPE: one wave per row of 128 ----------------
// swizzled=0: write plain (B,H,S,F), scaled by oscale. swizzled=1: write K tiled+swizzled
__global__ __launch_bounds__(256) void norm_rope(const u16* __restrict__ in,
                                                 u16* __restrict__ outp,
                                                 const float* __restrict__ nw,
                                                 const float* __restrict__ ctab,
                                                 const float* __restrict__ stab,
                                                 int swizzled, float oscale){
  int t = threadIdx.x, w = t>>6, l = t&63;
  size_t R = (size_t)blockIdx.x*4 + w;     // over B*H*S rows
  int p = (int)(R & (S_LEN-1));
  size_t base = R * HD;
  float x0 = bf2f(in[base + l]);
  float x1 = bf2f(in[base + 64 + l]);
  float ss = x0*x0 + x1*x1;
  #pragma unroll
  for (int m=1;m<64;m<<=1) ss += __shfl_xor(ss, m);
  float rms = sqrtf(ss * (1.0f/128.0f));
  float sc = oscale / (rms + 1e-6f);
  float xn0 = x0 * sc * nw[l];
  float xn1 = x1 * sc * nw[64+l];
  float c = ctab[(size_t)p*64 + l], s = stab[(size_t)p*64 + l];
  float o0 = xn0*c - xn1*s;
  float o1 = xn1*c + xn0*s;
  if (!swizzled){
    outp[base + l]      = f2bf(o0);
    outp[base + 64 + l] = f2bf(o1);
  } else {
    size_t plane = R >> 11;
    int kv = p & 63;
    size_t tb = (plane*(size_t)PLANE_ELEMS + (size_t)(p>>6)*8192) * 2;
    int b0 = (kv*256 + l*2)        ^ ((kv&7)<<4);
    int b1 = (kv*256 + (64+l)*2)   ^ ((kv&7)<<4);
    *(u16*)((char*)outp + tb + b0) = f2bf(o0);
    *(u16*)((char*)outp + tb + b1) = f2bf(o1);
  }
}

// ---------------- flash attention: 4 waves, QBLK=128 (32 rows/wave), KVBLK=64 ----------------
// each K/V LDS fragment feeds TWO q-fragments (halves LDS-read + addr VALU per FLOP)
__global__ __launch_bounds__(256,2) void attn_fwd(const u16* __restrict__ qn, // prescaled ATT_SCALE*LOG2E
                                                  const u16* __restrict__ kn, // tiled swizzled
                                                  const u16* __restrict__ vt, // V^T tiled swizzled+permuted
                                                  u16* __restrict__ attn_out){// (B,S,H,F)
  __shared__ u16 Klds[2][8192];     // [64 kv][128 f] swizzled
  __shared__ u16 Vlds[2][8192];     // [128 f][64 kv] swizzled+permuted
  int t = threadIdx.x, w = t>>6, l = t&63;
  int lr = l&15, lg = l>>4;

  // XCD-aware decomposition: plane pinned to one XCD (bid&7); 512 blocks
  int bid = blockIdx.x;                  // 0..511
  int xcd = bid & 7, j = bid >> 3;       // j 0..63
  int plane = xcd*4 + (j >> 4);          // 4 planes per XCD
  int qb = j & 15;
  int q0 = qb*128 + w*32;                // 32 q-rows per wave

  s8b qf[2][4];
  #pragma unroll
  for (int qi=0; qi<2; qi++)
    #pragma unroll
    for (int fc=0; fc<4; fc++)
      qf[qi][fc] = *(const s8b*)(qn + ((size_t)plane*S_LEN + q0 + qi*16 + lr)*HD + fc*32 + lg*8);

  float m[2], lsum[2];                   // per-lane (q = q0+qi*16+lr); log2 domain
  #pragma unroll
  for (int qi=0;qi<2;qi++){ m[qi] = -1e30f; lsum[qi] = 0.f; }
  f32x4 oacc[2][8];
  #pragma unroll
  for (int qi=0;qi<2;qi++)
    #pragma unroll
    for (int i=0;i<8;i++) oacc[qi][i] = f32x4{0.f,0.f,0.f,0.f};

  const u16* kbase = kn + (size_t)plane*PLANE_ELEMS;
  const u16* vbase = vt + (size_t)plane*PLANE_ELEMS;

  auto stage = [&](int buf, int kt){
    #pragma unroll
    for (int i=0;i<4;i++){
      gload16(kbase + (size_t)kt*8192 + w*2048 + i*512 + l*8, &Klds[buf][w*2048 + i*512]);
      gload16(vbase + (size_t)kt*8192 + w*2048 + i*512 + l*8, &Vlds[buf][w*2048 + i*512]);
    }
  };

  stage(0, 0);
  int cur = 0;
  for (int kt=0; kt<32; kt++){
    __syncthreads();                    // buf[cur] staged; buf[cur^1] reads done
    if (kt+1 < 32) stage(cur^1, kt+1);  // async loads fly under compute

    // swapped QK^T: sacc[c][qi][r] = S[kv=c*16+lg*4+r][q=qi*16+lr]  (log2 units)
    f32x4 sacc[4][2];
    #pragma unroll
    for (int c=0;c<4;c++)
      #pragma unroll
      for (int qi=0;qi<2;qi++) sacc[c][qi] = f32x4{0.f,0.f,0.f,0.f};
    __builtin_amdgcn_s_setprio(1);
    #pragma unroll
    for (int c=0;c<4;c++){
      int kv = c*16 + lr;
      #pragma unroll
      for (int fc=0; fc<4; fc++){
        int byte = (kv*256 + (fc*32 + lg*8)*2) ^ ((kv&7)<<4);
        s8b kf = *(const s8b*)((const char*)&Klds[cur][0] + byte);
        sacc[c][0] = mfma16(kf, qf[0][fc], sacc[c][0]);
        sacc[c][1] = mfma16(kf, qf[1][fc], sacc[c][1]);
      }
    }
    __builtin_amdgcn_s_setprio(0);

    // defer-max online softmax (log2 domain), per q-fragment
    float mx[2];
    #pragma unroll
    for (int qi=0;qi<2;qi++){
      float a0 = fmaxf(fmaxf(sacc[0][qi][0], sacc[0][qi][1]), fmaxf(sacc[0][qi][2], sacc[0][qi][3]));
      float a1 = fmaxf(fmaxf(sacc[1][qi][0], sacc[1][qi][1]), fmaxf(sacc[1][qi][2], sacc[1][qi][3]));
      float a2 = fmaxf(fmaxf(sacc[2][qi][0], sacc[2][qi][1]), fmaxf(sacc[2][qi][2], sacc[2][qi][3]));
      float a3 = fmaxf(fmaxf(sacc[3][qi][0], sacc[3][qi][1]), fmaxf(sacc[3][qi][2], sacc[3][qi][3]));
      mx[qi] = fmaxf(fmaxf(a0, a1), fmaxf(a2, a3));
    }
    bool need = (mx[0] > m[0] + 11.5f) || (mx[1] > m[1] + 11.5f);
    if (__any(need)){
      #pragma unroll
      for (int qi=0;qi<2;qi++){
        float v = mx[qi];
        v = fmaxf(v, __shfl_xor(v, 16));
        v = fmaxf(v, __shfl_xor(v, 32));
        v = fmaxf(m[qi], v);
        float al = exp2f(m[qi] - v);
        m[qi] = v; lsum[qi] *= al;
        float alr[4];
        #pragma unroll
        for (int r=0;r<4;r++) alr[r] = __shfl(al, lg*4 + r);
        #pragma unroll
        for (int i=0;i<8;i++)
          #pragma unroll
          for (int r=0;r<4;r++) oacc[qi][i][r] *= alr[r];
      }
    }
    float pv[2][4][4];
    #pragma unroll
    for (int qi=0;qi<2;qi++){
      float ls0=0.f, ls1=0.f, ls2=0.f, ls3=0.f;
      #pragma unroll
      for (int c=0;c<4;c++){
        float e0 = exp2f(sacc[c][qi][0] - m[qi]);
        float e1 = exp2f(sacc[c][qi][1] - m[qi]);
        float e2 = exp2f(sacc[c][qi][2] - m[qi]);
        float e3 = exp2f(sacc[c][qi][3] - m[qi]);
        pv[qi][c][0]=e0; pv[qi][c][1]=e1; pv[qi][c][2]=e2; pv[qi][c][3]=e3;
        ls0 += e0; ls1 += e1; ls2 += e2; ls3 += e3;
      }
      lsum[qi] += (ls0 + ls1) + (ls2 + ls3);
    }

    // pack P to bf16 A-frags (sigma order; V pi-permuted to match)
    s8b pa[2][2];
    #pragma unroll
    for (int qi=0;qi<2;qi++)
      #pragma unroll
      for (int kc=0;kc<2;kc++){
        union { s8b v; unsigned u[4]; } pu;
        pu.u[0] = cvtpk(pv[qi][2*kc][0],   pv[qi][2*kc][1]);
        pu.u[1] = cvtpk(pv[qi][2*kc][2],   pv[qi][2*kc][3]);
        pu.u[2] = cvtpk(pv[qi][2*kc+1][0], pv[qi][2*kc+1][1]);
        pu.u[3] = cvtpk(pv[qi][2*kc+1][2], pv[qi][2*kc+1][3]);
        pa[qi][kc] = pu.v;
      }

    // PV: O[q][f] += P[q][kv] * V[kv][f]; each vf feeds both q-frags
    __builtin_amdgcn_s_setprio(1);
    #pragma unroll
    for (int kc=0;kc<2;kc++){
      #pragma unroll
      for (int fc2=0; fc2<8; fc2++){
        int f = fc2*16 + lr;
        int byte = (f*128 + (kc*32 + lg*8)*2) ^ ((f&7)<<4);
        s8b vf = *(const s8b*)((const char*)&Vlds[cur][0] + byte);
        oacc[0][fc2] = mfma16(pa[0][kc], vf, oacc[0][fc2]);
        oacc[1][fc2] = mfma16(pa[1][kc], vf, oacc[1][fc2]);
      }
    }
    __builtin_amdgcn_s_setprio(0);
    cur ^= 1;
  }

  // final: reduce lsum across lg groups (per q = qi*16+lr), redistribute to rows
  int b = plane >> 4, h = plane & 15;
  #pragma unroll
  for (int qi=0;qi<2;qi++){
    float v = lsum[qi];
    v += __shfl_xor(v, 16);
    v += __shfl_xor(v, 32);
    v = 1.0f / v;
    float lir[4];
    #pragma unroll
    for (int r=0;r<4;r++) lir[r] = __shfl(v, lg*4 + r);
    #pragma unroll
    for (int fc2=0; fc2<8; fc2++){
      int f = fc2*16 + lr;
      #pragma unroll
      for (int r=0;r<4;r++){
        int row = q0 + qi*16 + lg*4 + r;
        float o = oacc[qi][fc2][r] * lir[r];
        attn_out[(((size_t)b*S_LEN + row)*NHEAD + h)*HD + f] = f2bf(o);
      }
    }
  }
}

// ---------------------------------------------------------------------------
extern "C" void kernel_launch(void* const* d_in, const int* in_sizes, int n_in,
                              void* d_out, int out_size, void* d_ws, size_t ws_size,
                              hipStream_t stream){
  const float* xq = (const float*)d_in[0];
  const float* xk = (const float*)d_in[1];
  const float* xv = (const float*)d_in[2];
  const float* WQ = (const float*)d_in[3];
  const float* WK = (const float*)d_in[4];
  const float* WV = (const float*)d_in[5];
  const float* WO = (const float*)d_in[6];
  const float* bQ = (const float*)d_in[7];
  const float* bK = (const float*)d_in[8];
  const float* bV = (const float*)d_in[9];
  const float* bO = (const float*)d_in[10];
  const float* qw = (const float*)d_in[11];
  const float* kw = (const float*)d_in[12];

  char* ws = (char*)d_ws;
  size_t off = 0;
  auto alloc = [&](size_t bytes)->void*{
    void* p = ws + off; off += (bytes + 255) & ~(size_t)255; return p;
  };
  const size_t ACT = (size_t)ROWS*DM*2;    // 16.78 MB (bf16 [4096][2048])
  const size_t WMT = (size_t)DM*DM*2;      // 8.39 MB
  u16* xqb  = (u16*)alloc(ACT);
  u16* xkb  = (u16*)alloc(ACT);
  u16* xvb  = (u16*)alloc(ACT);
  u16* WqT  = (u16*)alloc(WMT);
  u16* WkT  = (u16*)alloc(WMT);
  u16* WvT  = (u16*)alloc(WMT);
  u16* WoT  = (u16*)alloc(WMT);
  u16* qraw = (u16*)alloc(ACT);
  u16* kraw = (u16*)alloc(ACT);
  u16* knT  = (u16*)alloc(ACT);
  u16* vtS  = (u16*)alloc(ACT);
  u16* attn = (u16*)alloc(ACT);
  float* ctab = (float*)alloc((size_t)S_LEN*64*4);
  float* stab = (float*)alloc((size_t)S_LEN*64*4);
  if (off > ws_size) return;               // ws too small -> absmax will flag it

  const int n4 = ROWS*DM/4;                // 2097152
  cvt4x3<<<dim3(n4/256, 3), dim3(256), 0, stream>>>((const float4*)xq, (const float4*)xk,
                                                    (const float4*)xv, (uint2*)xqb,
                                                    (uint2*)xkb, (uint2*)xvb, n4);
  rope_tab<<<dim3(S_LEN*64/256), dim3(256), 0, stream>>>(ctab, stab);
  // W_Q/K/V: (H,D,F) -> [h*128+f][d]
  transpose_cvt<<<dim3(64,4,16), dim3(32,8), 0, stream>>>(WQ, WqT, 2048, 128, 2048);
  transpose_cvt<<<dim3(64,4,16), dim3(32,8), 0, stream>>>(WK, WkT, 2048, 128, 2048);
  transpose_cvt<<<dim3(64,4,16), dim3(32,8), 0, stream>>>(WV, WvT, 2048, 128, 2048);
  // W_O: [hf][m] -> [m][hf]
  transpose_cvt<<<dim3(64,64,1), dim3(32,8), 0, stream>>>(WO, WoT, 2048, 2048, 2048);

  gemm_bt<<<dim3(512), dim3(256), 0, stream>>>(xqb, WqT, bQ, qraw, 0);
  gemm_bt<<<dim3(512), dim3(256), 0, stream>>>(xkb, WkT, bK, kraw, 0);
  gemm_bt<<<dim3(512), dim3(256), 0, stream>>>(xvb, WvT, bV, vtS, 1);

  norm_rope<<<dim3(NPLANE*S_LEN/4), dim3(256), 0, stream>>>(qraw, qraw, qw, ctab, stab, 0, ATT_SCALE*LOG2E);
  norm_rope<<<dim3(NPLANE*S_LEN/4), dim3(256), 0, stream>>>(kraw, knT, kw, ctab, stab, 1, 1.0f);

  attn_fwd<<<dim3(512), dim3(256), 0, stream>>>(qraw, knT, vtS, attn);

  gemm_bt<<<dim3(512), dim3(256), 0, stream>>>(attn, WoT, bO, d_out, 2);
}

// Round 9
// 352.123 us; speedup vs baseline: 1.1836x; 1.0671x over previous
//
#include <hip/hip_runtime.h>
#include <stdint.h>

typedef unsigned short u16;
typedef __attribute__((ext_vector_type(8))) short  s8b;   // 8 bf16 (4 VGPRs)
typedef __attribute__((ext_vector_type(4))) float  f32x4;

#define S_LEN   2048
#define NHEAD   16
#define HD      128
#define DM      2048
#define NB      2
#define NPLANE  (NB*NHEAD)          // 32
#define ROWS    (NB*S_LEN)          // 4096 = M for all GEMMs
#define PLANE_ELEMS (S_LEN*HD)      // 262144
#define ATT_SCALE 0.08838834764831845f   // 1/sqrt(128)
#define LOG2E     1.4426950408889634f

__device__ __forceinline__ float bf2f(u16 u){
  union { unsigned u; float f; } x; x.u = ((unsigned)u) << 16; return x.f;
}
__device__ __forceinline__ u16 f2bf(float f){
  union { float f; unsigned u; } x; x.f = f;
  unsigned r = x.u + 0x7FFFu + ((x.u >> 16) & 1u);   // RNE
  return (u16)(r >> 16);
}
__device__ __forceinline__ unsigned cvtpk(float lo, float hi){
  unsigned r;
  asm("v_cvt_pk_bf16_f32 %0, %1, %2" : "=v"(r) : "v"(lo), "v"(hi));
  return r;
}

typedef const __attribute__((address_space(1))) unsigned int* gas1;
typedef __attribute__((address_space(3))) unsigned int* las3;
__device__ __forceinline__ void gload16(const void* g, void* l){
  // async global->LDS, dest = wave-uniform base + lane*16
  __builtin_amdgcn_global_load_lds((gas1)g, (las3)l, 16, 0, 0);
}

__device__ __forceinline__ f32x4 mfma16(s8b a, s8b b, f32x4 c){
  return __builtin_amdgcn_mfma_f32_16x16x32_bf16(a, b, c, 0, 0, 0);
}

// ---------------- elementwise f32 -> bf16, 3 tensors in one launch ----------------
__global__ __launch_bounds__(256) void cvt4x3(const float4* __restrict__ a,
                                              const float4* __restrict__ b,
                                              const float4* __restrict__ c,
                                              uint2* __restrict__ oa,
                                              uint2* __restrict__ ob,
                                              uint2* __restrict__ oc, int n4){
  int i = blockIdx.x*256 + threadIdx.x;
  if (i >= n4) return;
  const float4* src = (blockIdx.y == 0) ? a : (blockIdx.y == 1) ? b : c;
  uint2*       dst  = (blockIdx.y == 0) ? oa : (blockIdx.y == 1) ? ob : oc;
  float4 v = src[i];
  uint2 o;
  o.x = (unsigned)f2bf(v.x) | ((unsigned)f2bf(v.y) << 16);
  o.y = (unsigned)f2bf(v.z) | ((unsigned)f2bf(v.w) << 16);
  dst[i] = o;
}

// ---------------- tiled transpose + convert: in[z][R][C] f32 -> out[z][C][outStride] bf16 ----
__global__ __launch_bounds__(256) void transpose_cvt(const float* __restrict__ in,
                                                     u16* __restrict__ out,
                                                     int R, int C, int outStride){
  __shared__ float tile[32][33];
  int z = blockIdx.z;
  const float* inz = in + (size_t)z * R * C;
  u16* outz = out + (size_t)z * C * outStride;
  int r0 = blockIdx.x*32, c0 = blockIdx.y*32;
  int tx = threadIdx.x, ty = threadIdx.y;   // (32,8)
  #pragma unroll
  for (int i=0;i<4;i++)
    tile[ty*4+i][tx] = inz[(size_t)(r0+ty*4+i)*C + c0 + tx];
  __syncthreads();
  #pragma unroll
  for (int i=0;i<4;i++)
    outz[(size_t)(c0+ty*4+i)*outStride + r0 + tx] = f2bf(tile[tx][ty*4+i]);
}

// ---------------- RoPE table (f32) ----------------
__global__ __launch_bounds__(256) void rope_tab(float* __restrict__ ctab,
                                                float* __restrict__ stab){
  int i = blockIdx.x*256 + threadIdx.x;   // S_LEN*64
  int p = i >> 6, j = i & 63;
  float freq = exp2f(-(float)j * (13.287712379549449f/64.0f));  // 10000^(-j/64)
  float a = (float)p * freq;
  ctab[i] = cosf(a);
  stab[i] = sinf(a);
}

// ---------------- GEMM: A[4096][2048] x BT[2048][2048] bf16, counted-vmcnt pipeline ------
// 256x128 tile, BK=64, 8 waves (4Mx2N, 64x64 each), ring-6 half-slots (144KB LDS),
// prefetch depth 2 K-tiles, vmcnt(9) (never 0 in-loop), raw barriers + sched_barrier fences,
// both-sides (row&7)<<4 swizzle. grid: 1D 256 blocks x 512 thr, XCD swizzle.
// mode 0: out bf16 plain (B,H,S,F) | mode 1: V^T tiled+swizzled+pi-permuted | mode 2: f32+bias
__global__ __launch_bounds__(512) void gemm_bt(const u16* __restrict__ A,
                                               const u16* __restrict__ BT,
                                               const float* __restrict__ bias,
                                               void* __restrict__ out, int mode){
  const int K = 2048;
  const int NT = 32;                       // K/64
  __shared__ u16 lds[6*12288];             // 6 slots x 24KB: A-half [128][64] + B-half [64][64]
  const int t = threadIdx.x, w = t >> 6, l = t & 63;
  const int lr = l & 15, lg = l >> 4;
  const int wr = w >> 1, wc = w & 1;       // 4M x 2N waves, 64x64 output each
  int bid = blockIdx.x;
  int swz = (bid & 7)*32 + (bid >> 3);     // 256 % 8 == 0, bijective
  const int M0 = (swz >> 4) * 256, N0 = (swz & 15) * 128;

  f32x4 acc[4][4];
  #pragma unroll
  for (int i=0;i<4;i++)
    #pragma unroll
    for (int j=0;j<4;j++) acc[i][j] = f32x4{0.f,0.f,0.f,0.f};

  // stage half-tile h of (unwrapped) K-tile index ttu. Ring slot advances with ttu
  // (NOT the wrapped address tile — r8 bug: wrapped slot collided with live tile).
  // 3 gloads per wave. LDS linear per-row, kbyte' = kbyte ^ ((row&7)<<4), source
  // pre-inverse-swizzled (involution).
  auto stageH = [&](int ttu, int h){
    int slot = (2*ttu + h) % 6;
    int tt   = ttu & 31;
    char* base = (char*)&lds[slot*12288];
    #pragma unroll
    for (int j=0;j<2;j++){                       // A-half: 128 rows x 128B
      int d = w*2048 + j*1024 + l*16;
      int row = d >> 7;                          // 0..127
      int koff = ((l&7)*16) ^ ((row&7)<<4);
      gload16((const char*)A + ((size_t)(M0 + h*128 + row)*K + tt*64)*2 + koff,
              base + w*2048 + j*1024);
    }
    {                                            // B-half: 64 rows x 128B
      int d = w*1024 + l*16;
      int row = d >> 7;                          // 0..63
      int koff = ((l&7)*16) ^ ((row&7)<<4);
      gload16((const char*)BT + ((size_t)(N0 + h*64 + row)*K + tt*64)*2 + koff,
              base + 16384 + w*1024);
    }
  };

  // prologue: 2 K-tiles in flight (12 loads/wave), slots 0..3
  stageH(0,0); stageH(0,1); stageH(1,0); stageH(1,1);

  for (int kt=0; kt<NT; kt++){
    const char* Ab = (const char*)&lds[((2*kt + (wr>>1)) % 6)*12288];
    const char* Bb = (const char*)&lds[((2*kt + wc) % 6)*12288] + 16384;

    // ---- P0: issue H(t+2,0) -> slot 2kt+4; counted wait; barrier; hoist af; nj=0 ----
    stageH(kt+2, 0);
    asm volatile("s_waitcnt vmcnt(9)" ::: "memory");   // newest 9 = t+2h0,t+1h1,t+1h0 -> tile kt landed
    __builtin_amdgcn_s_barrier();
    __builtin_amdgcn_sched_barrier(0);

    s8b af[4][2];
    #pragma unroll
    for (int mi=0;mi<4;mi++)
      #pragma unroll
      for (int kc=0;kc<2;kc++){
        int rA = (wr&1)*64 + mi*16 + lr;
        af[mi][kc] = *(const s8b*)(Ab + rA*128 + ((kc*64 + lg*16) ^ ((rA&7)<<4)));
      }
    {
      s8b bf0, bf1;
      int rB = 0*16 + lr;
      bf0 = *(const s8b*)(Bb + rB*128 + ((0*64 + lg*16) ^ ((rB&7)<<4)));
      bf1 = *(const s8b*)(Bb + rB*128 + ((1*64 + lg*16) ^ ((rB&7)<<4)));
      __builtin_amdgcn_s_setprio(1);
      #pragma unroll
      for (int mi=0;mi<4;mi++){
        acc[mi][0] = mfma16(af[mi][0], bf0, acc[mi][0]);
        acc[mi][0] = mfma16(af[mi][1], bf1, acc[mi][0]);
      }
      __builtin_amdgcn_s_setprio(0);
    }
    // ---- P1: nj=1; fence + barrier (readers done before P2's issue) ----
    {
      s8b bf0, bf1;
      int rB = 1*16 + lr;
      bf0 = *(const s8b*)(Bb + rB*128 + ((0*64 + lg*16) ^ ((rB&7)<<4)));
      bf1 = *(const s8b*)(Bb + rB*128 + ((1*64 + lg*16) ^ ((rB&7)<<4)));
      __builtin_amdgcn_s_setprio(1);
      #pragma unroll
      for (int mi=0;mi<4;mi++){
        acc[mi][1] = mfma16(af[mi][0], bf0, acc[mi][1]);
        acc[mi][1] = mfma16(af[mi][1], bf1, acc[mi][1]);
      }
      __builtin_amdgcn_s_setprio(0);
    }
    __builtin_amdgcn_sched_barrier(0);
    __builtin_amdgcn_s_barrier();
    __builtin_amdgcn_sched_barrier(0);
    // ---- P2: issue H(t+2,1) -> slot 2kt+5; nj=2 ----
    stageH(kt+2, 1);
    {
      s8b bf0, bf1;
      int rB = 2*16 + lr;
      bf0 = *(const s8b*)(Bb + rB*128 + ((0*64 + lg*16) ^ ((rB&7)<<4)));
      bf1 = *(const s8b*)(Bb + rB*128 + ((1*64 + lg*16) ^ ((rB&7)<<4)));
      __builtin_amdgcn_s_setprio(1);
      #pragma unroll
      for (int mi=0;mi<4;mi++){
        acc[mi][2] = mfma16(af[mi][0], bf0, acc[mi][2]);
        acc[mi][2] = mfma16(af[mi][1], bf1, acc[mi][2]);
      }
      __builtin_amdgcn_s_setprio(0);
    }
    // ---- P3: nj=3; fence + barrier (readers done before next P0's issue) ----
    {
      s8b bf0, bf1;
      int rB = 3*16 + lr;
      bf0 = *(const s8b*)(Bb + rB*128 + ((0*64 + lg*16) ^ ((rB&7)<<4)));
      bf1 = *(const s8b*)(Bb + rB*128 + ((1*64 + lg*16) ^ ((rB&7)<<4)));
      __builtin_amdgcn_s_setprio(1);
      #pragma unroll
      for (int mi=0;mi<4;mi++){
        acc[mi][3] = mfma16(af[mi][0], bf0, acc[mi][3]);
        acc[mi][3] = mfma16(af[mi][1], bf1, acc[mi][3]);
      }
      __builtin_amdgcn_s_setprio(0);
    }
    __builtin_amdgcn_sched_barrier(0);
    __builtin_amdgcn_s_barrier();
    __builtin_amdgcn_sched_barrier(0);
  }
  asm volatile("s_waitcnt vmcnt(0)" ::: "memory");   // drain wrap-stages

  // epilogue: D layout col=lane&15, row=(lane>>4)*4+reg
  #pragma unroll
  for (int mi=0;mi<4;mi++){
    int growb = M0 + wr*64 + mi*16 + lg*4;
    #pragma unroll
    for (int nj=0;nj<4;nj++){
      int gcol = N0 + wc*64 + nj*16 + lr;
      float bv = bias[gcol];
      #pragma unroll
      for (int r=0;r<4;r++){
        int grow = growb + r;
        float v = acc[mi][nj][r] + bv;
        if (mode == 2){
          ((float*)out)[(size_t)grow*2048 + gcol] = v;
        } else {
          int b = grow >> 11, p = grow & 2047;
          int h = gcol >> 7,  f = gcol & 127;
          if (mode == 0){
            ((u16*)out)[(((size_t)(b*NHEAD+h))*S_LEN + p)*HD + f] = f2bf(v);
          } else {
            // V^T tile: pi-permute kv within 32 so PV B-frag matches in-reg P sigma order
            size_t base = ((size_t)(b*NHEAD+h)*PLANE_ELEMS + (size_t)(p>>6)*8192) * 2;
            int p6 = p & 63;
            int q_ = ((p6&12)<<1) | (p6&3) | ((p6&16)>>2);
            int kvp = (p6 & 32) | q_;
            int byte = (f*128 + kvp*2) ^ ((f&7)<<4);
            *(u16*)((char*)out + base + byte) = f2bf(v);
          }
        }
      }
    }
  }
}

// ---------------- RMSNorm + RoPE: one wave per row of 128 ----------------
__global__ __launch_bounds__(256) void norm_rope(const u16* __restrict__ in,
                                                 u16* __restrict__ outp,
                                                 const float* __restrict__ nw,
                                                 const float* __restrict__ ctab,
                                                 const float* __restrict__ stab,
                                                 int swizzled, float oscale){
  int t = threadIdx.x, w = t>>6, l = t&63;
  size_t R = (size_t)blockIdx.x*4 + w;     // over B*H*S rows
  int p = (int)(R & (S_LEN-1));
  size_t base = R * HD;
  float x0 = bf2f(in[base + l]);
  float x1 = bf2f(in[base + 64 + l]);
  float ss = x0*x0 + x1*x1;
  #pragma unroll
  for (int m=1;m<64;m<<=1) ss += __shfl_xor(ss, m);
  float rms = sqrtf(ss * (1.0f/128.0f));
  float sc = oscale / (rms + 1e-6f);
  float xn0 = x0 * sc * nw[l];
  float xn1 = x1 * sc * nw[64+l];
  float c = ctab[(size_t)p*64 + l], s = stab[(size_t)p*64 + l];
  float o0 = xn0*c - xn1*s;
  float o1 = xn1*c + xn0*s;
  if (!swizzled){
    outp[base + l]      = f2bf(o0);
    outp[base + 64 + l] = f2bf(o1);
  } else {
    size_t plane = R >> 11;
    int kv = p & 63;
    size_t tb = (plane*(size_t)PLANE_ELEMS + (size_t)(p>>6)*8192) * 2;
    int b0 = (kv*256 + l*2)        ^ ((kv&7)<<4);
    int b1 = (kv*256 + (64+l)*2)   ^ ((kv&7)<<4);
    *(u16*)((char*)outp + tb + b0) = f2bf(o0);
    *(u16*)((char*)outp + tb + b1) = f2bf(o1);
  }
}

// ---------------- flash attention: 4 waves, QBLK=128 (32 rows/wave), KVBLK=64 ----------------
__global__ __launch_bounds__(256,2) void attn_fwd(const u16* __restrict__ qn, // prescaled ATT_SCALE*LOG2E
                                                  const u16* __restrict__ kn, // tiled swizzled
                                                  const u16* __restrict__ vt, // V^T tiled swizzled+permuted
                                                  u16* __restrict__ attn_out){// (B,S,H,F)
  __shared__ u16 Klds[2][8192];     // [64 kv][128 f] swizzled
  __shared__ u16 Vlds[2][8192];     // [128 f][64 kv] swizzled+permuted
  int t = threadIdx.x, w = t>>6, l = t&63;
  int lr = l&15, lg = l>>4;

  int bid = blockIdx.x;                  // 0..511
  int xcd = bid & 7, j = bid >> 3;       // j 0..63
  int plane = xcd*4 + (j >> 4);          // 4 planes per XCD
  int qb = j & 15;
  int q0 = qb*128 + w*32;                // 32 q-rows per wave

  s8b qf[2][4];
  #pragma unroll
  for (int qi=0; qi<2; qi++)
    #pragma unroll
    for (int fc=0; fc<4; fc++)
      qf[qi][fc] = *(const s8b*)(qn + ((size_t)plane*S_LEN + q0 + qi*16 + lr)*HD + fc*32 + lg*8);

  float m[2], lsum[2];
  #pragma unroll
  for (int qi=0;qi<2;qi++){ m[qi] = -1e30f; lsum[qi] = 0.f; }
  f32x4 oacc[2][8];
  #pragma unroll
  for (int qi=0;qi<2;qi++)
    #pragma unroll
    for (int i=0;i<8;i++) oacc[qi][i] = f32x4{0.f,0.f,0.f,0.f};

  const u16* kbase = kn + (size_t)plane*PLANE_ELEMS;
  const u16* vbase = vt + (size_t)plane*PLANE_ELEMS;

  auto stage = [&](int buf, int kt){
    #pragma unroll
    for (int i=0;i<4;i++){
      gload16(kbase + (size_t)kt*8192 + w*2048 + i*512 + l*8, &Klds[buf][w*2048 + i*512]);
      gload16(vbase + (size_t)kt*8192 + w*2048 + i*512 + l*8, &Vlds[buf][w*2048 + i*512]);
    }
  };

  stage(0, 0);
  int cur = 0;
  for (int kt=0; kt<32; kt++){
    __syncthreads();
    if (kt+1 < 32) stage(cur^1, kt+1);

    f32x4 sacc[4][2];
    #pragma unroll
    for (int c=0;c<4;c++)
      #pragma unroll
      for (int qi=0;qi<2;qi++) sacc[c][qi] = f32x4{0.f,0.f,0.f,0.f};
    __builtin_amdgcn_s_setprio(1);
    #pragma unroll
    for (int c=0;c<4;c++){
      int kv = c*16 + lr;
      #pragma unroll
      for (int fc=0; fc<4; fc++){
        int byte = (kv*256 + (fc*32 + lg*8)*2) ^ ((kv&7)<<4);
        s8b kf = *(const s8b*)((const char*)&Klds[cur][0] + byte);
        sacc[c][0] = mfma16(kf, qf[0][fc], sacc[c][0]);
        sacc[c][1] = mfma16(kf, qf[1][fc], sacc[c][1]);
      }
    }
    __builtin_amdgcn_s_setprio(0);

    float mx[2];
    #pragma unroll
    for (int qi=0;qi<2;qi++){
      float a0 = fmaxf(fmaxf(sacc[0][qi][0], sacc[0][qi][1]), fmaxf(sacc[0][qi][2], sacc[0][qi][3]));
      float a1 = fmaxf(fmaxf(sacc[1][qi][0], sacc[1][qi][1]), fmaxf(sacc[1][qi][2], sacc[1][qi][3]));
      float a2 = fmaxf(fmaxf(sacc[2][qi][0], sacc[2][qi][1]), fmaxf(sacc[2][qi][2], sacc[2][qi][3]));
      float a3 = fmaxf(fmaxf(sacc[3][qi][0], sacc[3][qi][1]), fmaxf(sacc[3][qi][2], sacc[3][qi][3]));
      mx[qi] = fmaxf(fmaxf(a0, a1), fmaxf(a2, a3));
    }
    bool need = (mx[0] > m[0] + 11.5f) || (mx[1] > m[1] + 11.5f);
    if (__any(need)){
      #pragma unroll
      for (int qi=0;qi<2;qi++){
        float v = mx[qi];
        v = fmaxf(v, __shfl_xor(v, 16));
        v = fmaxf(v, __shfl_xor(v, 32));
        v = fmaxf(m[qi], v);
        float al = exp2f(m[qi] - v);
        m[qi] = v; lsum[qi] *= al;
        float alr[4];
        #pragma unroll
        for (int r=0;r<4;r++) alr[r] = __shfl(al, lg*4 + r);
        #pragma unroll
        for (int i=0;i<8;i++)
          #pragma unroll
          for (int r=0;r<4;r++) oacc[qi][i][r] *= alr[r];
      }
    }
    float pv[2][4][4];
    #pragma unroll
    for (int qi=0;qi<2;qi++){
      float ls0=0.f, ls1=0.f, ls2=0.f, ls3=0.f;
      #pragma unroll
      for (int c=0;c<4;c++){
        float e0 = exp2f(sacc[c][qi][0] - m[qi]);
        float e1 = exp2f(sacc[c][qi][1] - m[qi]);
        float e2 = exp2f(sacc[c][qi][2] - m[qi]);
        float e3 = exp2f(sacc[c][qi][3] - m[qi]);
        pv[qi][c][0]=e0; pv[qi][c][1]=e1; pv[qi][c][2]=e2; pv[qi][c][3]=e3;
        ls0 += e0; ls1 += e1; ls2 += e2; ls3 += e3;
      }
      lsum[qi] += (ls0 + ls1) + (ls2 + ls3);
    }

    s8b pa[2][2];
    #pragma unroll
    for (int qi=0;qi<2;qi++)
      #pragma unroll
      for (int kc=0;kc<2;kc++){
        union { s8b v; unsigned u[4]; } pu;
        pu.u[0] = cvtpk(pv[qi][2*kc][0],   pv[qi][2*kc][1]);
        pu.u[1] = cvtpk(pv[qi][2*kc][2],   pv[qi][2*kc][3]);
        pu.u[2] = cvtpk(pv[qi][2*kc+1][0], pv[qi][2*kc+1][1]);
        pu.u[3] = cvtpk(pv[qi][2*kc+1][2], pv[qi][2*kc+1][3]);
        pa[qi][kc] = pu.v;
      }

    __builtin_amdgcn_s_setprio(1);
    #pragma unroll
    for (int kc=0;kc<2;kc++){
      #pragma unroll
      for (int fc2=0; fc2<8; fc2++){
        int f = fc2*16 + lr;
        int byte = (f*128 + (kc*32 + lg*8)*2) ^ ((f&7)<<4);
        s8b vf = *(const s8b*)((const char*)&Vlds[cur][0] + byte);
        oacc[0][fc2] = mfma16(pa[0][kc], vf, oacc[0][fc2]);
        oacc[1][fc2] = mfma16(pa[1][kc], vf, oacc[1][fc2]);
      }
    }
    __builtin_amdgcn_s_setprio(0);
    cur ^= 1;
  }

  int b = plane >> 4, h = plane & 15;
  #pragma unroll
  for (int qi=0;qi<2;qi++){
    float v = lsum[qi];
    v += __shfl_xor(v, 16);
    v += __shfl_xor(v, 32);
    v = 1.0f / v;
    float lir[4];
    #pragma unroll
    for (int r=0;r<4;r++) lir[r] = __shfl(v, lg*4 + r);
    #pragma unroll
    for (int fc2=0; fc2<8; fc2++){
      int f = fc2*16 + lr;
      #pragma unroll
      for (int r=0;r<4;r++){
        int row = q0 + qi*16 + lg*4 + r;
        float o = oacc[qi][fc2][r] * lir[r];
        attn_out[(((size_t)b*S_LEN + row)*NHEAD + h)*HD + f] = f2bf(o);
      }
    }
  }
}

// ---------------------------------------------------------------------------
extern "C" void kernel_launch(void* const* d_in, const int* in_sizes, int n_in,
                              void* d_out, int out_size, void* d_ws, size_t ws_size,
                              hipStream_t stream){
  const float* xq = (const float*)d_in[0];
  const float* xk = (const float*)d_in[1];
  const float* xv = (const float*)d_in[2];
  const float* WQ = (const float*)d_in[3];
  const float* WK = (const float*)d_in[4];
  const float* WV = (const float*)d_in[5];
  const float* WO = (const float*)d_in[6];
  const float* bQ = (const float*)d_in[7];
  const float* bK = (const float*)d_in[8];
  const float* bV = (const float*)d_in[9];
  const float* bO = (const float*)d_in[10];
  const float* qw = (const float*)d_in[11];
  const float* kw = (const float*)d_in[12];

  char* ws = (char*)d_ws;
  size_t off = 0;
  auto alloc = [&](size_t bytes)->void*{
    void* p = ws + off; off += (bytes + 255) & ~(size_t)255; return p;
  };
  const size_t ACT = (size_t)ROWS*DM*2;    // 16.78 MB (bf16 [4096][2048])
  const size_t WMT = (size_t)DM*DM*2;      // 8.39 MB
  u16* xqb  = (u16*)alloc(ACT);
  u16* xkb  = (u16*)alloc(ACT);
  u16* xvb  = (u16*)alloc(ACT);
  u16* WqT  = (u16*)alloc(WMT);
  u16* WkT  = (u16*)alloc(WMT);
  u16* WvT  = (u16*)alloc(WMT);
  u16* WoT  = (u16*)alloc(WMT);
  u16* qraw = (u16*)alloc(ACT);
  u16* kraw = (u16*)alloc(ACT);
  u16* knT  = (u16*)alloc(ACT);
  u16* vtS  = (u16*)alloc(ACT);
  u16* attn = (u16*)alloc(ACT);
  float* ctab = (float*)alloc((size_t)S_LEN*64*4);
  float* stab = (float*)alloc((size_t)S_LEN*64*4);
  if (off > ws_size) return;               // ws too small -> absmax will flag it

  const int n4 = ROWS*DM/4;                // 2097152
  cvt4x3<<<dim3(n4/256, 3), dim3(256), 0, stream>>>((const float4*)xq, (const float4*)xk,
                                                    (const float4*)xv, (uint2*)xqb,
                                                    (uint2*)xkb, (uint2*)xvb, n4);
  rope_tab<<<dim3(S_LEN*64/256), dim3(256), 0, stream>>>(ctab, stab);
  // W_Q/K/V: (H,D,F) -> [h*128+f][d]
  transpose_cvt<<<dim3(64,4,16), dim3(32,8), 0, stream>>>(WQ, WqT, 2048, 128, 2048);
  transpose_cvt<<<dim3(64,4,16), dim3(32,8), 0, stream>>>(WK, WkT, 2048, 128, 2048);
  transpose_cvt<<<dim3(64,4,16), dim3(32,8), 0, stream>>>(WV, WvT, 2048, 128, 2048);
  // W_O: [hf][m] -> [m][hf]
  transpose_cvt<<<dim3(64,64,1), dim3(32,8), 0, stream>>>(WO, WoT, 2048, 2048, 2048);

  gemm_bt<<<dim3(256), dim3(512), 0, stream>>>(xqb, WqT, bQ, qraw, 0);
  gemm_bt<<<dim3(256), dim3(512), 0, stream>>>(xkb, WkT, bK, kraw, 0);
  gemm_bt<<<dim3(256), dim3(512), 0, stream>>>(xvb, WvT, bV, vtS, 1);

  norm_rope<<<dim3(NPLANE*S_LEN/4), dim3(256), 0, stream>>>(qraw, qraw, qw, ctab, stab, 0, ATT_SCALE*LOG2E);
  norm_rope<<<dim3(NPLANE*S_LEN/4), dim3(256), 0, stream>>>(kraw, knT, kw, ctab, stab, 1, 1.0f);

  attn_fwd<<<dim3(512), dim3(256), 0, stream>>>(qraw, knT, vtS, attn);

  gemm_bt<<<dim3(256), dim3(512), 0, stream>>>(attn, WoT, bO, d_out, 2);
}

// Round 10
// 346.353 us; speedup vs baseline: 1.2033x; 1.0167x over previous
//
#include <hip/hip_runtime.h>
#include <stdint.h>

typedef unsigned short u16;
typedef __attribute__((ext_vector_type(8))) short  s8b;   // 8 bf16 (4 VGPRs)
typedef __attribute__((ext_vector_type(4))) float  f32x4;

#define S_LEN   2048
#define NHEAD   16
#define HD      128
#define DM      2048
#define NB      2
#define NPLANE  (NB*NHEAD)          // 32
#define ROWS    (NB*S_LEN)          // 4096 = M for all GEMMs
#define PLANE_ELEMS (S_LEN*HD)      // 262144
#define ATT_SCALE 0.08838834764831845f   // 1/sqrt(128)
#define LOG2E     1.4426950408889634f

__device__ __forceinline__ float bf2f(u16 u){
  union { unsigned u; float f; } x; x.u = ((unsigned)u) << 16; return x.f;
}
__device__ __forceinline__ u16 f2bf(float f){
  union { float f; unsigned u; } x; x.f = f;
  unsigned r = x.u + 0x7FFFu + ((x.u >> 16) & 1u);   // RNE
  return (u16)(r >> 16);
}
__device__ __forceinline__ unsigned cvtpk(float lo, float hi){
  unsigned r;
  asm("v_cvt_pk_bf16_f32 %0, %1, %2" : "=v"(r) : "v"(lo), "v"(hi));
  return r;
}

typedef const __attribute__((address_space(1))) unsigned int* gas1;
typedef __attribute__((address_space(3))) unsigned int* las3;
__device__ __forceinline__ void gload16(const void* g, void* l){
  // async global->LDS, dest = wave-uniform base + lane*16
  __builtin_amdgcn_global_load_lds((gas1)g, (las3)l, 16, 0, 0);
}

__device__ __forceinline__ f32x4 mfma16(s8b a, s8b b, f32x4 c){
  return __builtin_amdgcn_mfma_f32_16x16x32_bf16(a, b, c, 0, 0, 0);
}

// ---------------- elementwise f32 -> bf16, 3 tensors in one launch ----------------
__global__ __launch_bounds__(256) void cvt4x3(const float4* __restrict__ a,
                                              const float4* __restrict__ b,
                                              const float4* __restrict__ c,
                                              uint2* __restrict__ oa,
                                              uint2* __restrict__ ob,
                                              uint2* __restrict__ oc, int n4){
  int i = blockIdx.x*256 + threadIdx.x;
  if (i >= n4) return;
  const float4* src = (blockIdx.y == 0) ? a : (blockIdx.y == 1) ? b : c;
  uint2*       dst  = (blockIdx.y == 0) ? oa : (blockIdx.y == 1) ? ob : oc;
  float4 v = src[i];
  uint2 o;
  o.x = (unsigned)f2bf(v.x) | ((unsigned)f2bf(v.y) << 16);
  o.y = (unsigned)f2bf(v.z) | ((unsigned)f2bf(v.w) << 16);
  dst[i] = o;
}

// ---------------- tiled transpose + convert: in[z][R][C] f32 -> out[z][C][outStride] bf16 ----
__global__ __launch_bounds__(256) void transpose_cvt(const float* __restrict__ in,
                                                     u16* __restrict__ out,
                                                     int R, int C, int outStride){
  __shared__ float tile[32][33];
  int z = blockIdx.z;
  const float* inz = in + (size_t)z * R * C;
  u16* outz = out + (size_t)z * C * outStride;
  int r0 = blockIdx.x*32, c0 = blockIdx.y*32;
  int tx = threadIdx.x, ty = threadIdx.y;   // (32,8)
  #pragma unroll
  for (int i=0;i<4;i++)
    tile[ty*4+i][tx] = inz[(size_t)(r0+ty*4+i)*C + c0 + tx];
  __syncthreads();
  #pragma unroll
  for (int i=0;i<4;i++)
    outz[(size_t)(c0+ty*4+i)*outStride + r0 + tx] = f2bf(tile[tx][ty*4+i]);
}

// ---------------- RoPE table (f32) ----------------
__global__ __launch_bounds__(256) void rope_tab(float* __restrict__ ctab,
                                                float* __restrict__ stab){
  int i = blockIdx.x*256 + threadIdx.x;   // S_LEN*64
  int p = i >> 6, j = i & 63;
  float freq = exp2f(-(float)j * (13.287712379549449f/64.0f));  // 10000^(-j/64)
  float a = (float)p * freq;
  ctab[i] = cosf(a);
  stab[i] = sinf(a);
}

// ---------------- GEMM: A[4096][2048] x BT[2048][2048] bf16, counted-vmcnt pipeline ------
// 256x128 tile, BK=64, 8 waves (4Mx2N, 64x64 each), ring-6 half-slots (144KB LDS),
// prefetch depth 2 K-tiles, vmcnt(9) (never 0 in-loop), 2 phases x 16 MFMA, 2 barriers/K-tile,
// both-sides (row&7)<<4 swizzle. grid: 1D 256 blocks x 512 thr, XCD swizzle.
// mode 0: out bf16 plain (B,H,S,F) | mode 1: V^T tiled+swizzled+pi-permuted | mode 2: f32+bias
__global__ __launch_bounds__(512) void gemm_bt(const u16* __restrict__ A,
                                               const u16* __restrict__ BT,
                                               const float* __restrict__ bias,
                                               void* __restrict__ out, int mode){
  const int K = 2048;
  const int NT = 32;                       // K/64
  __shared__ u16 lds[6*12288];             // 6 slots x 24KB: A-half [128][64] + B-half [64][64]
  const int t = threadIdx.x, w = t >> 6, l = t & 63;
  const int lr = l & 15, lg = l >> 4;
  const int wr = w >> 1, wc = w & 1;       // 4M x 2N waves, 64x64 output each
  int bid = blockIdx.x;
  int swz = (bid & 7)*32 + (bid >> 3);     // 256 % 8 == 0, bijective
  const int M0 = (swz >> 4) * 256, N0 = (swz & 15) * 128;

  f32x4 acc[4][4];
  #pragma unroll
  for (int i=0;i<4;i++)
    #pragma unroll
    for (int j=0;j<4;j++) acc[i][j] = f32x4{0.f,0.f,0.f,0.f};

  // stage half-tile h of (unwrapped) K-tile index ttu; slot from unwrapped index.
  auto stageH = [&](int ttu, int h){
    int slot = (2*ttu + h) % 6;
    int tt   = ttu & 31;
    char* base = (char*)&lds[slot*12288];
    #pragma unroll
    for (int j=0;j<2;j++){                       // A-half: 128 rows x 128B
      int d = w*2048 + j*1024 + l*16;
      int row = d >> 7;                          // 0..127
      int koff = ((l&7)*16) ^ ((row&7)<<4);
      gload16((const char*)A + ((size_t)(M0 + h*128 + row)*K + tt*64)*2 + koff,
              base + w*2048 + j*1024);
    }
    {                                            // B-half: 64 rows x 128B
      int d = w*1024 + l*16;
      int row = d >> 7;                          // 0..63
      int koff = ((l&7)*16) ^ ((row&7)<<4);
      gload16((const char*)BT + ((size_t)(N0 + h*64 + row)*K + tt*64)*2 + koff,
              base + 16384 + w*1024);
    }
  };

  // prologue: 2 K-tiles in flight (12 loads/wave), slots 0..3
  stageH(0,0); stageH(0,1); stageH(1,0); stageH(1,1);

  for (int kt=0; kt<NT; kt++){
    const char* Ab = (const char*)&lds[((2*kt + (wr>>1)) % 6)*12288];
    const char* Bb = (const char*)&lds[((2*kt + wc) % 6)*12288] + 16384;

    // ---- P0: issue H(t+2,0); counted wait; barrier; af + bf(nj0,1); 16 MFMA ----
    stageH(kt+2, 0);
    asm volatile("s_waitcnt vmcnt(9)" ::: "memory");   // tile kt fully landed
    __builtin_amdgcn_s_barrier();
    __builtin_amdgcn_sched_barrier(0);

    s8b af[4][2];
    #pragma unroll
    for (int mi=0;mi<4;mi++)
      #pragma unroll
      for (int kc=0;kc<2;kc++){
        int rA = (wr&1)*64 + mi*16 + lr;
        af[mi][kc] = *(const s8b*)(Ab + rA*128 + ((kc*64 + lg*16) ^ ((rA&7)<<4)));
      }
    {
      s8b bf[2][2];
      #pragma unroll
      for (int nj=0;nj<2;nj++){
        int rB = nj*16 + lr;
        bf[nj][0] = *(const s8b*)(Bb + rB*128 + ((0*64 + lg*16) ^ ((rB&7)<<4)));
        bf[nj][1] = *(const s8b*)(Bb + rB*128 + ((1*64 + lg*16) ^ ((rB&7)<<4)));
      }
      __builtin_amdgcn_s_setprio(1);
      #pragma unroll
      for (int mi=0;mi<4;mi++)
        #pragma unroll
        for (int nj=0;nj<2;nj++){
          acc[mi][nj] = mfma16(af[mi][0], bf[nj][0], acc[mi][nj]);
          acc[mi][nj] = mfma16(af[mi][1], bf[nj][1], acc[mi][nj]);
        }
      __builtin_amdgcn_s_setprio(0);
    }
    // ---- P1: issue H(t+2,1); bf(nj2,3); 16 MFMA; end barrier ----
    stageH(kt+2, 1);
    {
      s8b bf[2][2];
      #pragma unroll
      for (int nj=0;nj<2;nj++){
        int rB = (nj+2)*16 + lr;
        bf[nj][0] = *(const s8b*)(Bb + rB*128 + ((0*64 + lg*16) ^ ((rB&7)<<4)));
        bf[nj][1] = *(const s8b*)(Bb + rB*128 + ((1*64 + lg*16) ^ ((rB&7)<<4)));
      }
      __builtin_amdgcn_s_setprio(1);
      #pragma unroll
      for (int mi=0;mi<4;mi++)
        #pragma unroll
        for (int nj=0;nj<2;nj++){
          acc[mi][nj+2] = mfma16(af[mi][0], bf[nj][0], acc[mi][nj+2]);
          acc[mi][nj+2] = mfma16(af[mi][1], bf[nj][1], acc[mi][nj+2]);
        }
      __builtin_amdgcn_s_setprio(0);
    }
    __builtin_amdgcn_sched_barrier(0);
    __builtin_amdgcn_s_barrier();
    __builtin_amdgcn_sched_barrier(0);
  }
  asm volatile("s_waitcnt vmcnt(0)" ::: "memory");   // drain wrap-stages

  // epilogue: D layout col=lane&15, row=(lane>>4)*4+reg
  #pragma unroll
  for (int mi=0;mi<4;mi++){
    int growb = M0 + wr*64 + mi*16 + lg*4;
    #pragma unroll
    for (int nj=0;nj<4;nj++){
      int gcol = N0 + wc*64 + nj*16 + lr;
      float bv = bias[gcol];
      #pragma unroll
      for (int r=0;r<4;r++){
        int grow = growb + r;
        float v = acc[mi][nj][r] + bv;
        if (mode == 2){
          ((float*)out)[(size_t)grow*2048 + gcol] = v;
        } else {
          int b = grow >> 11, p = grow & 2047;
          int h = gcol >> 7,  f = gcol & 127;
          if (mode == 0){
            ((u16*)out)[(((size_t)(b*NHEAD+h))*S_LEN + p)*HD + f] = f2bf(v);
          } else {
            // V^T tile: pi-permute kv within 32 so PV B-frag matches in-reg P sigma order
            size_t base = ((size_t)(b*NHEAD+h)*PLANE_ELEMS + (size_t)(p>>6)*8192) * 2;
            int p6 = p & 63;
            int q_ = ((p6&12)<<1) | (p6&3) | ((p6&16)>>2);
            int kvp = (p6 & 32) | q_;
            int byte = (f*128 + kvp*2) ^ ((f&7)<<4);
            *(u16*)((char*)out + base + byte) = f2bf(v);
          }
        }
      }
    }
  }
}

// ---------------- RMSNorm + RoPE: one wave per row of 128 ----------------
__global__ __launch_bounds__(256) void norm_rope(const u16* __restrict__ in,
                                                 u16* __restrict__ outp,
                                                 const float* __restrict__ nw,
                                                 const float* __restrict__ ctab,
                                                 const float* __restrict__ stab,
                                                 int swizzled, float oscale){
  int t = threadIdx.x, w = t>>6, l = t&63;
  size_t R = (size_t)blockIdx.x*4 + w;     // over B*H*S rows
  int p = (int)(R & (S_LEN-1));
  size_t base = R * HD;
  float x0 = bf2f(in[base + l]);
  float x1 = bf2f(in[base + 64 + l]);
  float ss = x0*x0 + x1*x1;
  #pragma unroll
  for (int m=1;m<64;m<<=1) ss += __shfl_xor(ss, m);
  float rms = sqrtf(ss * (1.0f/128.0f));
  float sc = oscale / (rms + 1e-6f);
  float xn0 = x0 * sc * nw[l];
  float xn1 = x1 * sc * nw[64+l];
  float c = ctab[(size_t)p*64 + l], s = stab[(size_t)p*64 + l];
  float o0 = xn0*c - xn1*s;
  float o1 = xn1*c + xn0*s;
  if (!swizzled){
    outp[base + l]      = f2bf(o0);
    outp[base + 64 + l] = f2bf(o1);
  } else {
    size_t plane = R >> 11;
    int kv = p & 63;
    size_t tb = (plane*(size_t)PLANE_ELEMS + (size_t)(p>>6)*8192) * 2;
    int b0 = (kv*256 + l*2)        ^ ((kv&7)<<4);
    int b1 = (kv*256 + (64+l)*2)   ^ ((kv&7)<<4);
    *(u16*)((char*)outp + tb + b0) = f2bf(o0);
    *(u16*)((char*)outp + tb + b1) = f2bf(o1);
  }
}

// ---------------- flash attention: 4 waves, QBLK=128 (32 rows/wave), KVBLK=64 ----------------
// swapped QK^T; m folded into MFMA C-init (no per-score sub); denominator via ones-MFMA
// (no per-score adds, no final cross-lane reduce); defer-max thr 11.5 (m init 0)
__global__ __launch_bounds__(256,2) void attn_fwd(const u16* __restrict__ qn, // prescaled ATT_SCALE*LOG2E
                                                  const u16* __restrict__ kn, // tiled swizzled
                                                  const u16* __restrict__ vt, // V^T tiled swizzled+permuted
                                                  u16* __restrict__ attn_out){// (B,S,H,F)
  __shared__ u16 Klds[2][8192];     // [64 kv][128 f] swizzled
  __shared__ u16 Vlds[2][8192];     // [128 f][64 kv] swizzled+permuted
  int t = threadIdx.x, w = t>>6, l = t&63;
  int lr = l&15, lg = l>>4;

  int bid = blockIdx.x;                  // 0..511
  int xcd = bid & 7, j = bid >> 3;       // j 0..63
  int plane = xcd*4 + (j >> 4);          // 4 planes per XCD
  int qb = j & 15;
  int q0 = qb*128 + w*32;                // 32 q-rows per wave

  const s8b ones = { (short)0x3F80, (short)0x3F80, (short)0x3F80, (short)0x3F80,
                     (short)0x3F80, (short)0x3F80, (short)0x3F80, (short)0x3F80 };

  s8b qf[2][4];
  #pragma unroll
  for (int qi=0; qi<2; qi++)
    #pragma unroll
    for (int fc=0; fc<4; fc++)
      qf[qi][fc] = *(const s8b*)(qn + ((size_t)plane*S_LEN + q0 + qi*16 + lr)*HD + fc*32 + lg*8);

  float m[2];                            // per-lane running max (q = q0+qi*16+lr), log2 domain
  m[0] = 0.f; m[1] = 0.f;
  f32x4 lacc[2];                         // denominators, rows q = lg*4+r (same as oacc)
  lacc[0] = f32x4{0.f,0.f,0.f,0.f};
  lacc[1] = f32x4{0.f,0.f,0.f,0.f};
  f32x4 oacc[2][8];
  #pragma unroll
  for (int qi=0;qi<2;qi++)
    #pragma unroll
    for (int i=0;i<8;i++) oacc[qi][i] = f32x4{0.f,0.f,0.f,0.f};

  const u16* kbase = kn + (size_t)plane*PLANE_ELEMS;
  const u16* vbase = vt + (size_t)plane*PLANE_ELEMS;

  auto stage = [&](int buf, int kt){
    #pragma unroll
    for (int i=0;i<4;i++){
      gload16(kbase + (size_t)kt*8192 + w*2048 + i*512 + l*8, &Klds[buf][w*2048 + i*512]);
      gload16(vbase + (size_t)kt*8192 + w*2048 + i*512 + l*8, &Vlds[buf][w*2048 + i*512]);
    }
  };

  stage(0, 0);
  int cur = 0;
  for (int kt=0; kt<32; kt++){
    __syncthreads();
    if (kt+1 < 32) stage(cur^1, kt+1);

    // swapped QK^T with C-init = -m  ->  sacc = S - m directly
    f32x4 sacc[4][2];
    #pragma unroll
    for (int c=0;c<4;c++){
      sacc[c][0] = f32x4{-m[0],-m[0],-m[0],-m[0]};
      sacc[c][1] = f32x4{-m[1],-m[1],-m[1],-m[1]};
    }
    __builtin_amdgcn_s_setprio(1);
    #pragma unroll
    for (int c=0;c<4;c++){
      int kv = c*16 + lr;
      #pragma unroll
      for (int fc=0; fc<4; fc++){
        int byte = (kv*256 + (fc*32 + lg*8)*2) ^ ((kv&7)<<4);
        s8b kf = *(const s8b*)((const char*)&Klds[cur][0] + byte);
        sacc[c][0] = mfma16(kf, qf[0][fc], sacc[c][0]);
        sacc[c][1] = mfma16(kf, qf[1][fc], sacc[c][1]);
      }
    }
    __builtin_amdgcn_s_setprio(0);

    // defer-max: trigger iff any (S - m) > 11.5
    float mx[2];
    #pragma unroll
    for (int qi=0;qi<2;qi++){
      float a0 = fmaxf(fmaxf(sacc[0][qi][0], sacc[0][qi][1]), fmaxf(sacc[0][qi][2], sacc[0][qi][3]));
      float a1 = fmaxf(fmaxf(sacc[1][qi][0], sacc[1][qi][1]), fmaxf(sacc[1][qi][2], sacc[1][qi][3]));
      float a2 = fmaxf(fmaxf(sacc[2][qi][0], sacc[2][qi][1]), fmaxf(sacc[2][qi][2], sacc[2][qi][3]));
      float a3 = fmaxf(fmaxf(sacc[3][qi][0], sacc[3][qi][1]), fmaxf(sacc[3][qi][2], sacc[3][qi][3]));
      mx[qi] = fmaxf(fmaxf(a0, a1), fmaxf(a2, a3));
    }
    bool need = (mx[0] > 11.5f) || (mx[1] > 11.5f);
    if (__any(need)){
      #pragma unroll
      for (int qi=0;qi<2;qi++){
        float v = mx[qi];
        v = fmaxf(v, __shfl_xor(v, 16));
        v = fmaxf(v, __shfl_xor(v, 32));
        float delta = fmaxf(v, 0.f);         // uniform across the lg-group for q=lr
        float al = exp2f(-delta);
        m[qi] += delta;
        #pragma unroll
        for (int c=0;c<4;c++)
          #pragma unroll
          for (int r=0;r<4;r++) sacc[c][qi][r] -= delta;
        float alr[4];
        #pragma unroll
        for (int r=0;r<4;r++) alr[r] = __shfl(al, lg*4 + r);
        #pragma unroll
        for (int i=0;i<8;i++)
          #pragma unroll
          for (int r=0;r<4;r++) oacc[qi][i][r] *= alr[r];
        #pragma unroll
        for (int r=0;r<4;r++) lacc[qi][r] *= alr[r];
      }
    }
    // p = exp2(sacc); no subs, no scalar sum (denominator via ones-MFMA below)
    float pv[2][4][4];
    #pragma unroll
    for (int qi=0;qi<2;qi++)
      #pragma unroll
      for (int c=0;c<4;c++){
        pv[qi][c][0] = exp2f(sacc[c][qi][0]);
        pv[qi][c][1] = exp2f(sacc[c][qi][1]);
        pv[qi][c][2] = exp2f(sacc[c][qi][2]);
        pv[qi][c][3] = exp2f(sacc[c][qi][3]);
      }

    s8b pa[2][2];
    #pragma unroll
    for (int qi=0;qi<2;qi++)
      #pragma unroll
      for (int kc=0;kc<2;kc++){
        union { s8b v; unsigned u[4]; } pu;
        pu.u[0] = cvtpk(pv[qi][2*kc][0],   pv[qi][2*kc][1]);
        pu.u[1] = cvtpk(pv[qi][2*kc][2],   pv[qi][2*kc][3]);
        pu.u[2] = cvtpk(pv[qi][2*kc+1][0], pv[qi][2*kc+1][1]);
        pu.u[3] = cvtpk(pv[qi][2*kc+1][2], pv[qi][2*kc+1][3]);
        pa[qi][kc] = pu.v;
      }

    __builtin_amdgcn_s_setprio(1);
    #pragma unroll
    for (int kc=0;kc<2;kc++){
      lacc[0] = mfma16(pa[0][kc], ones, lacc[0]);   // row-sums: denominator, same row map as oacc
      lacc[1] = mfma16(pa[1][kc], ones, lacc[1]);
      #pragma unroll
      for (int fc2=0; fc2<8; fc2++){
        int f = fc2*16 + lr;
        int byte = (f*128 + (kc*32 + lg*8)*2) ^ ((f&7)<<4);
        s8b vf = *(const s8b*)((const char*)&Vlds[cur][0] + byte);
        oacc[0][fc2] = mfma16(pa[0][kc], vf, oacc[0][fc2]);
        oacc[1][fc2] = mfma16(pa[1][kc], vf, oacc[1][fc2]);
      }
    }
    __builtin_amdgcn_s_setprio(0);
    cur ^= 1;
  }

  // epilogue: in-lane normalize (lacc rows == oacc rows), no shfl
  int b = plane >> 4, h = plane & 15;
  #pragma unroll
  for (int qi=0;qi<2;qi++){
    float inv[4];
    #pragma unroll
    for (int r=0;r<4;r++) inv[r] = 1.0f / lacc[qi][r];
    #pragma unroll
    for (int fc2=0; fc2<8; fc2++){
      int f = fc2*16 + lr;
      #pragma unroll
      for (int r=0;r<4;r++){
        int row = q0 + qi*16 + lg*4 + r;
        float o = oacc[qi][fc2][r] * inv[r];
        attn_out[(((size_t)b*S_LEN + row)*NHEAD + h)*HD + f] = f2bf(o);
      }
    }
  }
}

// ---------------------------------------------------------------------------
extern "C" void kernel_launch(void* const* d_in, const int* in_sizes, int n_in,
                              void* d_out, int out_size, void* d_ws, size_t ws_size,
                              hipStream_t stream){
  const float* xq = (const float*)d_in[0];
  const float* xk = (const float*)d_in[1];
  const float* xv = (const float*)d_in[2];
  const float* WQ = (const float*)d_in[3];
  const float* WK = (const float*)d_in[4];
  const float* WV = (const float*)d_in[5];
  const float* WO = (const float*)d_in[6];
  const float* bQ = (const float*)d_in[7];
  const float* bK = (const float*)d_in[8];
  const float* bV = (const float*)d_in[9];
  const float* bO = (const float*)d_in[10];
  const float* qw = (const float*)d_in[11];
  const float* kw = (const float*)d_in[12];

  char* ws = (char*)d_ws;
  size_t off = 0;
  auto alloc = [&](size_t bytes)->void*{
    void* p = ws + off; off += (bytes + 255) & ~(size_t)255; return p;
  };
  const size_t ACT = (size_t)ROWS*DM*2;    // 16.78 MB (bf16 [4096][2048])
  const size_t WMT = (size_t)DM*DM*2;      // 8.39 MB
  u16* xqb  = (u16*)alloc(ACT);
  u16* xkb  = (u16*)alloc(ACT);
  u16* xvb  = (u16*)alloc(ACT);
  u16* WqT  = (u16*)alloc(WMT);
  u16* WkT  = (u16*)alloc(WMT);
  u16* WvT  = (u16*)alloc(WMT);
  u16* WoT  = (u16*)alloc(WMT);
  u16* qraw = (u16*)alloc(ACT);
  u16* kraw = (u16*)alloc(ACT);
  u16* knT  = (u16*)alloc(ACT);
  u16* vtS  = (u16*)alloc(ACT);
  u16* attn = (u16*)alloc(ACT);
  float* ctab = (float*)alloc((size_t)S_LEN*64*4);
  float* stab = (float*)alloc((size_t)S_LEN*64*4);
  if (off > ws_size) return;               // ws too small -> absmax will flag it

  const int n4 = ROWS*DM/4;                // 2097152
  cvt4x3<<<dim3(n4/256, 3), dim3(256), 0, stream>>>((const float4*)xq, (const float4*)xk,
                                                    (const float4*)xv, (uint2*)xqb,
                                                    (uint2*)xkb, (uint2*)xvb, n4);
  rope_tab<<<dim3(S_LEN*64/256), dim3(256), 0, stream>>>(ctab, stab);
  // W_Q/K/V: (H,D,F) -> [h*128+f][d]
  transpose_cvt<<<dim3(64,4,16), dim3(32,8), 0, stream>>>(WQ, WqT, 2048, 128, 2048);
  transpose_cvt<<<dim3(64,4,16), dim3(32,8), 0, stream>>>(WK, WkT, 2048, 128, 2048);
  transpose_cvt<<<dim3(64,4,16), dim3(32,8), 0, stream>>>(WV, WvT, 2048, 128, 2048);
  // W_O: [hf][m] -> [m][hf]
  transpose_cvt<<<dim3(64,64,1), dim3(32,8), 0, stream>>>(WO, WoT, 2048, 2048, 2048);

  gemm_bt<<<dim3(256), dim3(512), 0, stream>>>(xqb, WqT, bQ, qraw, 0);
  gemm_bt<<<dim3(256), dim3(512), 0, stream>>>(xkb, WkT, bK, kraw, 0);
  gemm_bt<<<dim3(256), dim3(512), 0, stream>>>(xvb, WvT, bV, vtS, 1);

  norm_rope<<<dim3(NPLANE*S_LEN/4), dim3(256), 0, stream>>>(qraw, qraw, qw, ctab, stab, 0, ATT_SCALE*LOG2E);
  norm_rope<<<dim3(NPLANE*S_LEN/4), dim3(256), 0, stream>>>(kraw, knT, kw, ctab, stab, 1, 1.0f);

  attn_fwd<<<dim3(512), dim3(256), 0, stream>>>(qraw, knT, vtS, attn);

  gemm_bt<<<dim3(256), dim3(512), 0, stream>>>(attn, WoT, bO, d_out, 2);
}

// Round 11
// 342.558 us; speedup vs baseline: 1.2166x; 1.0111x over previous
//
#include <hip/hip_runtime.h>
#include <stdint.h>

typedef unsigned short u16;
typedef __attribute__((ext_vector_type(8))) short  s8b;   // 8 bf16 (4 VGPRs)
typedef __attribute__((ext_vector_type(4))) float  f32x4;

#define S_LEN   2048
#define NHEAD   16
#define HD      128
#define DM      2048
#define NB      2
#define NPLANE  (NB*NHEAD)          // 32
#define ROWS    (NB*S_LEN)          // 4096 = M for all GEMMs
#define PLANE_ELEMS (S_LEN*HD)      // 262144
#define ATT_SCALE 0.08838834764831845f   // 1/sqrt(128)
#define LOG2E     1.4426950408889634f

__device__ __forceinline__ float bf2f(u16 u){
  union { unsigned u; float f; } x; x.u = ((unsigned)u) << 16; return x.f;
}
__device__ __forceinline__ u16 f2bf(float f){
  union { float f; unsigned u; } x; x.f = f;
  unsigned r = x.u + 0x7FFFu + ((x.u >> 16) & 1u);   // RNE
  return (u16)(r >> 16);
}
__device__ __forceinline__ unsigned cvtpk(float lo, float hi){
  unsigned r;
  asm("v_cvt_pk_bf16_f32 %0, %1, %2" : "=v"(r) : "v"(lo), "v"(hi));
  return r;
}

typedef const __attribute__((address_space(1))) unsigned int* gas1;
typedef __attribute__((address_space(3))) unsigned int* las3;
__device__ __forceinline__ void gload16(const void* g, void* l){
  // async global->LDS, dest = wave-uniform base + lane*16
  __builtin_amdgcn_global_load_lds((gas1)g, (las3)l, 16, 0, 0);
}

__device__ __forceinline__ f32x4 mfma16(s8b a, s8b b, f32x4 c){
  return __builtin_amdgcn_mfma_f32_16x16x32_bf16(a, b, c, 0, 0, 0);
}

// ---------------- elementwise f32 -> bf16, 3 tensors in one launch ----------------
__global__ __launch_bounds__(256) void cvt4x3(const float4* __restrict__ a,
                                              const float4* __restrict__ b,
                                              const float4* __restrict__ c,
                                              uint2* __restrict__ oa,
                                              uint2* __restrict__ ob,
                                              uint2* __restrict__ oc, int n4){
  int i = blockIdx.x*256 + threadIdx.x;
  if (i >= n4) return;
  const float4* src = (blockIdx.y == 0) ? a : (blockIdx.y == 1) ? b : c;
  uint2*       dst  = (blockIdx.y == 0) ? oa : (blockIdx.y == 1) ? ob : oc;
  float4 v = src[i];
  uint2 o;
  o.x = (unsigned)f2bf(v.x) | ((unsigned)f2bf(v.y) << 16);
  o.y = (unsigned)f2bf(v.z) | ((unsigned)f2bf(v.w) << 16);
  dst[i] = o;
}

// ---------------- tiled transpose + convert: in[z][R][C] f32 -> out[z][C][outStride] bf16 ----
__global__ __launch_bounds__(256) void transpose_cvt(const float* __restrict__ in,
                                                     u16* __restrict__ out,
                                                     int R, int C, int outStride){
  __shared__ float tile[32][33];
  int z = blockIdx.z;
  const float* inz = in + (size_t)z * R * C;
  u16* outz = out + (size_t)z * C * outStride;
  int r0 = blockIdx.x*32, c0 = blockIdx.y*32;
  int tx = threadIdx.x, ty = threadIdx.y;   // (32,8)
  #pragma unroll
  for (int i=0;i<4;i++)
    tile[ty*4+i][tx] = inz[(size_t)(r0+ty*4+i)*C + c0 + tx];
  __syncthreads();
  #pragma unroll
  for (int i=0;i<4;i++)
    outz[(size_t)(c0+ty*4+i)*outStride + r0 + tx] = f2bf(tile[tx][ty*4+i]);
}

// ---------------- RoPE table (f32) ----------------
__global__ __launch_bounds__(256) void rope_tab(float* __restrict__ ctab,
                                                float* __restrict__ stab){
  int i = blockIdx.x*256 + threadIdx.x;   // S_LEN*64
  int p = i >> 6, j = i & 63;
  float freq = exp2f(-(float)j * (13.287712379549449f/64.0f));  // 10000^(-j/64)
  float a = (float)p * freq;
  ctab[i] = cosf(a);
  stab[i] = sinf(a);
}

// ---------------- GEMM: A[4096][2048] x BT[2048][2048] bf16, counted-vmcnt pipeline ------
// 256x128 tile, BK=64, 8 waves (4Mx2N, 64x64 each), ring-6 half-slots (144KB LDS),
// prefetch depth 2 K-tiles, vmcnt(9) (never 0 in-loop), 2 phases x 16 MFMA, 2 barriers/K-tile,
// both-sides (row&7)<<4 swizzle. grid: 1D 256 blocks x 512 thr, XCD swizzle.
// mode 0: out bf16 plain (B,H,S,F) | mode 1: V fragment-linear (16x1KB frags per kv-tile) |
// mode 2: f32+bias
__global__ __launch_bounds__(512) void gemm_bt(const u16* __restrict__ A,
                                               const u16* __restrict__ BT,
                                               const float* __restrict__ bias,
                                               void* __restrict__ out, int mode){
  const int K = 2048;
  const int NT = 32;                       // K/64
  __shared__ u16 lds[6*12288];             // 6 slots x 24KB: A-half [128][64] + B-half [64][64]
  const int t = threadIdx.x, w = t >> 6, l = t & 63;
  const int lr = l & 15, lg = l >> 4;
  const int wr = w >> 1, wc = w & 1;       // 4M x 2N waves, 64x64 output each
  int bid = blockIdx.x;
  int swz = (bid & 7)*32 + (bid >> 3);     // 256 % 8 == 0, bijective
  const int M0 = (swz >> 4) * 256, N0 = (swz & 15) * 128;

  f32x4 acc[4][4];
  #pragma unroll
  for (int i=0;i<4;i++)
    #pragma unroll
    for (int j=0;j<4;j++) acc[i][j] = f32x4{0.f,0.f,0.f,0.f};

  // stage half-tile h of (unwrapped) K-tile index ttu; slot from unwrapped index.
  auto stageH = [&](int ttu, int h){
    int slot = (2*ttu + h) % 6;
    int tt   = ttu & 31;
    char* base = (char*)&lds[slot*12288];
    #pragma unroll
    for (int j=0;j<2;j++){                       // A-half: 128 rows x 128B
      int d = w*2048 + j*1024 + l*16;
      int row = d >> 7;                          // 0..127
      int koff = ((l&7)*16) ^ ((row&7)<<4);
      gload16((const char*)A + ((size_t)(M0 + h*128 + row)*K + tt*64)*2 + koff,
              base + w*2048 + j*1024);
    }
    {                                            // B-half: 64 rows x 128B
      int d = w*1024 + l*16;
      int row = d >> 7;                          // 0..63
      int koff = ((l&7)*16) ^ ((row&7)<<4);
      gload16((const char*)BT + ((size_t)(N0 + h*64 + row)*K + tt*64)*2 + koff,
              base + 16384 + w*1024);
    }
  };

  // prologue: 2 K-tiles in flight (12 loads/wave), slots 0..3
  stageH(0,0); stageH(0,1); stageH(1,0); stageH(1,1);

  for (int kt=0; kt<NT; kt++){
    const char* Ab = (const char*)&lds[((2*kt + (wr>>1)) % 6)*12288];
    const char* Bb = (const char*)&lds[((2*kt + wc) % 6)*12288] + 16384;

    // ---- P0: issue H(t+2,0); counted wait; barrier; af + bf(nj0,1); 16 MFMA ----
    stageH(kt+2, 0);
    asm volatile("s_waitcnt vmcnt(9)" ::: "memory");   // tile kt fully landed
    __builtin_amdgcn_s_barrier();
    __builtin_amdgcn_sched_barrier(0);

    s8b af[4][2];
    #pragma unroll
    for (int mi=0;mi<4;mi++)
      #pragma unroll
      for (int kc=0;kc<2;kc++){
        int rA = (wr&1)*64 + mi*16 + lr;
        af[mi][kc] = *(const s8b*)(Ab + rA*128 + ((kc*64 + lg*16) ^ ((rA&7)<<4)));
      }
    {
      s8b bf[2][2];
      #pragma unroll
      for (int nj=0;nj<2;nj++){
        int rB = nj*16 + lr;
        bf[nj][0] = *(const s8b*)(Bb + rB*128 + ((0*64 + lg*16) ^ ((rB&7)<<4)));
        bf[nj][1] = *(const s8b*)(Bb + rB*128 + ((1*64 + lg*16) ^ ((rB&7)<<4)));
      }
      __builtin_amdgcn_s_setprio(1);
      #pragma unroll
      for (int mi=0;mi<4;mi++)
        #pragma unroll
        for (int nj=0;nj<2;nj++){
          acc[mi][nj] = mfma16(af[mi][0], bf[nj][0], acc[mi][nj]);
          acc[mi][nj] = mfma16(af[mi][1], bf[nj][1], acc[mi][nj]);
        }
      __builtin_amdgcn_s_setprio(0);
    }
    // ---- P1: issue H(t+2,1); bf(nj2,3); 16 MFMA; end barrier ----
    stageH(kt+2, 1);
    {
      s8b bf[2][2];
      #pragma unroll
      for (int nj=0;nj<2;nj++){
        int rB = (nj+2)*16 + lr;
        bf[nj][0] = *(const s8b*)(Bb + rB*128 + ((0*64 + lg*16) ^ ((rB&7)<<4)));
        bf[nj][1] = *(const s8b*)(Bb + rB*128 + ((1*64 + lg*16) ^ ((rB&7)<<4)));
      }
      __builtin_amdgcn_s_setprio(1);
      #pragma unroll
      for (int mi=0;mi<4;mi++)
        #pragma unroll
        for (int nj=0;nj<2;nj++){
          acc[mi][nj+2] = mfma16(af[mi][0], bf[nj][0], acc[mi][nj+2]);
          acc[mi][nj+2] = mfma16(af[mi][1], bf[nj][1], acc[mi][nj+2]);
        }
      __builtin_amdgcn_s_setprio(0);
    }
    __builtin_amdgcn_sched_barrier(0);
    __builtin_amdgcn_s_barrier();
    __builtin_amdgcn_sched_barrier(0);
  }
  asm volatile("s_waitcnt vmcnt(0)" ::: "memory");   // drain wrap-stages

  // epilogue: D layout col=lane&15, row=(lane>>4)*4+reg
  #pragma unroll
  for (int mi=0;mi<4;mi++){
    int growb = M0 + wr*64 + mi*16 + lg*4;
    #pragma unroll
    for (int nj=0;nj<4;nj++){
      int gcol = N0 + wc*64 + nj*16 + lr;
      float bv = bias[gcol];
      #pragma unroll
      for (int r=0;r<4;r++){
        int grow = growb + r;
        float v = acc[mi][nj][r] + bv;
        if (mode == 2){
          ((float*)out)[(size_t)grow*2048 + gcol] = v;
        } else {
          int b = grow >> 11, p = grow & 2047;
          int h = gcol >> 7,  f = gcol & 127;
          if (mode == 0){
            ((u16*)out)[(((size_t)(b*NHEAD+h))*S_LEN + p)*HD + f] = f2bf(v);
          } else {
            // V fragment-linear: 16 frags x 1KB per kv-tile; sigma-permute folded in.
            // frag = kc*8 + (f>>4); lane = lgv*16 + (f&15); elem j = kvp&7.
            size_t base = ((size_t)(b*NHEAD+h)*PLANE_ELEMS)*2 + (size_t)(p>>6)*16384;
            int p6 = p & 63;
            int q_ = ((p6&12)<<1) | (p6&3) | ((p6&16)>>2);
            int kvp = (p6 & 32) | q_;
            int kc = kvp >> 5, lgv = (kvp >> 3) & 3, jv = kvp & 7;
            int off = (kc*8 + (f>>4))*1024 + (lgv*16 + (f&15))*16 + jv*2;
            *(u16*)((char*)out + base + off) = f2bf(v);
          }
        }
      }
    }
  }
}

// ---------------- RMSNorm + RoPE: one wave per row of 128 ----------------
__global__ __launch_bounds__(256) void norm_rope(const u16* __restrict__ in,
                                                 u16* __restrict__ outp,
                                                 const float* __restrict__ nw,
                                                 const float* __restrict__ ctab,
                                                 const float* __restrict__ stab,
                                                 int swizzled, float oscale){
  int t = threadIdx.x, w = t>>6, l = t&63;
  size_t R = (size_t)blockIdx.x*4 + w;     // over B*H*S rows
  int p = (int)(R & (S_LEN-1));
  size_t base = R * HD;
  float x0 = bf2f(in[base + l]);
  float x1 = bf2f(in[base + 64 + l]);
  float ss = x0*x0 + x1*x1;
  #pragma unroll
  for (int m=1;m<64;m<<=1) ss += __shfl_xor(ss, m);
  float rms = sqrtf(ss * (1.0f/128.0f));
  float sc = oscale / (rms + 1e-6f);
  float xn0 = x0 * sc * nw[l];
  float xn1 = x1 * sc * nw[64+l];
  float c = ctab[(size_t)p*64 + l], s = stab[(size_t)p*64 + l];
  float o0 = xn0*c - xn1*s;
  float o1 = xn1*c + xn0*s;
  if (!swizzled){
    outp[base + l]      = f2bf(o0);
    outp[base + 64 + l] = f2bf(o1);
  } else {
    size_t plane = R >> 11;
    int kv = p & 63;
    size_t tb = (plane*(size_t)PLANE_ELEMS + (size_t)(p>>6)*8192) * 2;
    int b0 = (kv*256 + l*2)        ^ ((kv&7)<<4);
    int b1 = (kv*256 + (64+l)*2)   ^ ((kv&7)<<4);
    *(u16*)((char*)outp + tb + b0) = f2bf(o0);
    *(u16*)((char*)outp + tb + b1) = f2bf(o1);
  }
}

// ---------------- flash attention: 4 waves, QBLK=128 (32 rows/wave), KVBLK=64 ----------------
// K LDS-staged (dbuf 32KB); V global->register (fragment-linear, VMEM pipe);
// no defer-max (m==0, worst-case bounded: S*log2e <= 16.3 -> lacc <= 1.7e8 in f32);
// denominator via ones-MFMA.
__global__ __launch_bounds__(256,2) void attn_fwd(const u16* __restrict__ qn, // prescaled ATT_SCALE*LOG2E
                                                  const u16* __restrict__ kn, // tiled swizzled
                                                  const u16* __restrict__ vt, // V fragment-linear
                                                  u16* __restrict__ attn_out){// (B,S,H,F)
  __shared__ u16 Klds[2][8192];     // [64 kv][128 f] swizzled
  int t = threadIdx.x, w = t>>6, l = t&63;
  int lr = l&15, lg = l>>4;

  int bid = blockIdx.x;                  // 0..511
  int xcd = bid & 7, j = bid >> 3;       // j 0..63
  int plane = xcd*4 + (j >> 4);          // 4 planes per XCD
  int qb = j & 15;
  int q0 = qb*128 + w*32;                // 32 q-rows per wave

  const s8b ones = { (short)0x3F80, (short)0x3F80, (short)0x3F80, (short)0x3F80,
                     (short)0x3F80, (short)0x3F80, (short)0x3F80, (short)0x3F80 };

  s8b qf[2][4];
  #pragma unroll
  for (int qi=0; qi<2; qi++)
    #pragma unroll
    for (int fc=0; fc<4; fc++)
      qf[qi][fc] = *(const s8b*)(qn + ((size_t)plane*S_LEN + q0 + qi*16 + lr)*HD + fc*32 + lg*8);

  f32x4 lacc[2];                         // denominators, rows q = lg*4+r (same map as oacc)
  lacc[0] = f32x4{0.f,0.f,0.f,0.f};
  lacc[1] = f32x4{0.f,0.f,0.f,0.f};
  f32x4 oacc[2][8];
  #pragma unroll
  for (int qi=0;qi<2;qi++)
    #pragma unroll
    for (int i=0;i<8;i++) oacc[qi][i] = f32x4{0.f,0.f,0.f,0.f};

  const u16* kbase = kn + (size_t)plane*PLANE_ELEMS;
  const char* vbase = (const char*)vt + (size_t)plane*PLANE_ELEMS*2;

  auto stage = [&](int buf, int kt){     // K only: 4 gloads/wave
    #pragma unroll
    for (int i=0;i<4;i++)
      gload16(kbase + (size_t)kt*8192 + w*2048 + i*512 + l*8, &Klds[buf][w*2048 + i*512]);
  };

  stage(0, 0);
  int cur = 0;
  for (int kt=0; kt<32; kt++){
    __syncthreads();                     // Klds[cur] staged; prior reads done
    if (kt+1 < 32) stage(cur^1, kt+1);

    const char* vb = vbase + (size_t)kt*16384;
    // issue V kc=0 fragment loads early (land under QK^T)
    s8b vf0[8];
    #pragma unroll
    for (int fc2=0; fc2<8; fc2++)
      vf0[fc2] = *(const s8b*)(vb + fc2*1024 + l*16);

    // swapped QK^T: sacc[c][qi][r] = S[kv=c*16+lg*4+r][q=qi*16+lr]  (log2 units)
    f32x4 sacc[4][2];
    #pragma unroll
    for (int c=0;c<4;c++){
      sacc[c][0] = f32x4{0.f,0.f,0.f,0.f};
      sacc[c][1] = f32x4{0.f,0.f,0.f,0.f};
    }
    __builtin_amdgcn_s_setprio(1);
    #pragma unroll
    for (int c=0;c<4;c++){
      int kv = c*16 + lr;
      #pragma unroll
      for (int fc=0; fc<4; fc++){
        int byte = (kv*256 + (fc*32 + lg*8)*2) ^ ((kv&7)<<4);
        s8b kf = *(const s8b*)((const char*)&Klds[cur][0] + byte);
        sacc[c][0] = mfma16(kf, qf[0][fc], sacc[c][0]);
        sacc[c][1] = mfma16(kf, qf[1][fc], sacc[c][1]);
      }
    }
    __builtin_amdgcn_s_setprio(0);

    // issue V kc=1 fragment loads (land under softmax)
    s8b vf1[8];
    #pragma unroll
    for (int fc2=0; fc2<8; fc2++)
      vf1[fc2] = *(const s8b*)(vb + (8+fc2)*1024 + l*16);

    // p = exp2(S) directly (no max subtraction needed: bounded)
    float pv[2][4][4];
    #pragma unroll
    for (int qi=0;qi<2;qi++)
      #pragma unroll
      for (int c=0;c<4;c++){
        pv[qi][c][0] = exp2f(sacc[c][qi][0]);
        pv[qi][c][1] = exp2f(sacc[c][qi][1]);
        pv[qi][c][2] = exp2f(sacc[c][qi][2]);
        pv[qi][c][3] = exp2f(sacc[c][qi][3]);
      }

    s8b pa[2][2];
    #pragma unroll
    for (int qi=0;qi<2;qi++)
      #pragma unroll
      for (int kc=0;kc<2;kc++){
        union { s8b v; unsigned u[4]; } pu;
        pu.u[0] = cvtpk(pv[qi][2*kc][0],   pv[qi][2*kc][1]);
        pu.u[1] = cvtpk(pv[qi][2*kc][2],   pv[qi][2*kc][3]);
        pu.u[2] = cvtpk(pv[qi][2*kc+1][0], pv[qi][2*kc+1][1]);
        pu.u[3] = cvtpk(pv[qi][2*kc+1][2], pv[qi][2*kc+1][3]);
        pa[qi][kc] = pu.v;
      }

    __builtin_amdgcn_s_setprio(1);
    lacc[0] = mfma16(pa[0][0], ones, lacc[0]);
    lacc[1] = mfma16(pa[1][0], ones, lacc[1]);
    #pragma unroll
    for (int fc2=0; fc2<8; fc2++){
      oacc[0][fc2] = mfma16(pa[0][0], vf0[fc2], oacc[0][fc2]);
      oacc[1][fc2] = mfma16(pa[1][0], vf0[fc2], oacc[1][fc2]);
    }
    lacc[0] = mfma16(pa[0][1], ones, lacc[0]);
    lacc[1] = mfma16(pa[1][1], ones, lacc[1]);
    #pragma unroll
    for (int fc2=0; fc2<8; fc2++){
      oacc[0][fc2] = mfma16(pa[0][1], vf1[fc2], oacc[0][fc2]);
      oacc[1][fc2] = mfma16(pa[1][1], vf1[fc2], oacc[1][fc2]);
    }
    __builtin_amdgcn_s_setprio(0);
    cur ^= 1;
  }

  // epilogue: in-lane normalize (lacc rows == oacc rows), no shfl
  int b = plane >> 4, h = plane & 15;
  #pragma unroll
  for (int qi=0;qi<2;qi++){
    float inv[4];
    #pragma unroll
    for (int r=0;r<4;r++) inv[r] = 1.0f / lacc[qi][r];
    #pragma unroll
    for (int fc2=0; fc2<8; fc2++){
      int f = fc2*16 + lr;
      #pragma unroll
      for (int r=0;r<4;r++){
        int row = q0 + qi*16 + lg*4 + r;
        float o = oacc[qi][fc2][r] * inv[r];
        attn_out[(((size_t)b*S_LEN + row)*NHEAD + h)*HD + f] = f2bf(o);
      }
    }
  }
}

// ---------------------------------------------------------------------------
extern "C" void kernel_launch(void* const* d_in, const int* in_sizes, int n_in,
                              void* d_out, int out_size, void* d_ws, size_t ws_size,
                              hipStream_t stream){
  const float* xq = (const float*)d_in[0];
  const float* xk = (const float*)d_in[1];
  const float* xv = (const float*)d_in[2];
  const float* WQ = (const float*)d_in[3];
  const float* WK = (const float*)d_in[4];
  const float* WV = (const float*)d_in[5];
  const float* WO = (const float*)d_in[6];
  const float* bQ = (const float*)d_in[7];
  const float* bK = (const float*)d_in[8];
  const float* bV = (const float*)d_in[9];
  const float* bO = (const float*)d_in[10];
  const float* qw = (const float*)d_in[11];
  const float* kw = (const float*)d_in[12];

  char* ws = (char*)d_ws;
  size_t off = 0;
  auto alloc = [&](size_t bytes)->void*{
    void* p = ws + off; off += (bytes + 255) & ~(size_t)255; return p;
  };
  const size_t ACT = (size_t)ROWS*DM*2;    // 16.78 MB (bf16 [4096][2048])
  const size_t WMT = (size_t)DM*DM*2;      // 8.39 MB
  u16* xqb  = (u16*)alloc(ACT);
  u16* xkb  = (u16*)alloc(ACT);
  u16* xvb  = (u16*)alloc(ACT);
  u16* WqT  = (u16*)alloc(WMT);
  u16* WkT  = (u16*)alloc(WMT);
  u16* WvT  = (u16*)alloc(WMT);
  u16* WoT  = (u16*)alloc(WMT);
  u16* qraw = (u16*)alloc(ACT);
  u16* kraw = (u16*)alloc(ACT);
  u16* knT  = (u16*)alloc(ACT);
  u16* vtS  = (u16*)alloc(ACT);
  u16* attn = (u16*)alloc(ACT);
  float* ctab = (float*)alloc((size_t)S_LEN*64*4);
  float* stab = (float*)alloc((size_t)S_LEN*64*4);
  if (off > ws_size) return;               // ws too small -> absmax will flag it

  const int n4 = ROWS*DM/4;                // 2097152
  cvt4x3<<<dim3(n4/256, 3), dim3(256), 0, stream>>>((const float4*)xq, (const float4*)xk,
                                                    (const float4*)xv, (uint2*)xqb,
                                                    (uint2*)xkb, (uint2*)xvb, n4);
  rope_tab<<<dim3(S_LEN*64/256), dim3(256), 0, stream>>>(ctab, stab);
  // W_Q/K/V: (H,D,F) -> [h*128+f][d]
  transpose_cvt<<<dim3(64,4,16), dim3(32,8), 0, stream>>>(WQ, WqT, 2048, 128, 2048);
  transpose_cvt<<<dim3(64,4,16), dim3(32,8), 0, stream>>>(WK, WkT, 2048, 128, 2048);
  transpose_cvt<<<dim3(64,4,16), dim3(32,8), 0, stream>>>(WV, WvT, 2048, 128, 2048);
  // W_O: [hf][m] -> [m][hf]
  transpose_cvt<<<dim3(64,64,1), dim3(32,8), 0, stream>>>(WO, WoT, 2048, 2048, 2048);

  gemm_bt<<<dim3(256), dim3(512), 0, stream>>>(xqb, WqT, bQ, qraw, 0);
  gemm_bt<<<dim3(256), dim3(512), 0, stream>>>(xkb, WkT, bK, kraw, 0);
  gemm_bt<<<dim3(256), dim3(512), 0, stream>>>(xvb, WvT, bV, vtS, 1);

  norm_rope<<<dim3(NPLANE*S_LEN/4), dim3(256), 0, stream>>>(qraw, qraw, qw, ctab, stab, 0, ATT_SCALE*LOG2E);
  norm_rope<<<dim3(NPLANE*S_LEN/4), dim3(256), 0, stream>>>(kraw, knT, kw, ctab, stab, 1, 1.0f);

  attn_fwd<<<dim3(512), dim3(256), 0, stream>>>(qraw, knT, vtS, attn);

  gemm_bt<<<dim3(256), dim3(512), 0, stream>>>(attn, WoT, bO, d_out, 2);
}

// Round 12
// 334.267 us; speedup vs baseline: 1.2468x; 1.0248x over previous
//
#include <hip/hip_runtime.h>
#include <stdint.h>

typedef unsigned short u16;
typedef __attribute__((ext_vector_type(8))) short  s8b;   // 8 bf16 (4 VGPRs)
typedef __attribute__((ext_vector_type(4))) float  f32x4;

#define S_LEN   2048
#define NHEAD   16
#define HD      128
#define DM      2048
#define NB      2
#define NPLANE  (NB*NHEAD)          // 32
#define ROWS    (NB*S_LEN)          // 4096 = M for all GEMMs
#define PLANE_ELEMS (S_LEN*HD)      // 262144
#define ATT_SCALE 0.08838834764831845f   // 1/sqrt(128)
#define LOG2E     1.4426950408889634f

__device__ __forceinline__ float bf2f(u16 u){
  union { unsigned u; float f; } x; x.u = ((unsigned)u) << 16; return x.f;
}
__device__ __forceinline__ u16 f2bf(float f){
  union { float f; unsigned u; } x; x.f = f;
  unsigned r = x.u + 0x7FFFu + ((x.u >> 16) & 1u);   // RNE
  return (u16)(r >> 16);
}
__device__ __forceinline__ unsigned cvtpk(float lo, float hi){
  unsigned r;
  asm("v_cvt_pk_bf16_f32 %0, %1, %2" : "=v"(r) : "v"(lo), "v"(hi));
  return r;
}

typedef const __attribute__((address_space(1))) unsigned int* gas1;
typedef __attribute__((address_space(3))) unsigned int* las3;
__device__ __forceinline__ void gload16(const void* g, void* l){
  // async global->LDS, dest = wave-uniform base + lane*16
  __builtin_amdgcn_global_load_lds((gas1)g, (las3)l, 16, 0, 0);
}

__device__ __forceinline__ f32x4 mfma16(s8b a, s8b b, f32x4 c){
  return __builtin_amdgcn_mfma_f32_16x16x32_bf16(a, b, c, 0, 0, 0);
}

// ---------------- elementwise f32 -> bf16, 3 tensors in one launch ----------------
__global__ __launch_bounds__(256) void cvt4x3(const float4* __restrict__ a,
                                              const float4* __restrict__ b,
                                              const float4* __restrict__ c,
                                              uint2* __restrict__ oa,
                                              uint2* __restrict__ ob,
                                              uint2* __restrict__ oc, int n4){
  int i = blockIdx.x*256 + threadIdx.x;
  if (i >= n4) return;
  const float4* src = (blockIdx.y == 0) ? a : (blockIdx.y == 1) ? b : c;
  uint2*       dst  = (blockIdx.y == 0) ? oa : (blockIdx.y == 1) ? ob : oc;
  float4 v = src[i];
  uint2 o;
  o.x = (unsigned)f2bf(v.x) | ((unsigned)f2bf(v.y) << 16);
  o.y = (unsigned)f2bf(v.z) | ((unsigned)f2bf(v.w) << 16);
  dst[i] = o;
}

// ---------------- tiled transpose + convert: in[z][R][C] f32 -> out[z][C][outStride] bf16 ----
__global__ __launch_bounds__(256) void transpose_cvt(const float* __restrict__ in,
                                                     u16* __restrict__ out,
                                                     int R, int C, int outStride){
  __shared__ float tile[32][33];
  int z = blockIdx.z;
  const float* inz = in + (size_t)z * R * C;
  u16* outz = out + (size_t)z * C * outStride;
  int r0 = blockIdx.x*32, c0 = blockIdx.y*32;
  int tx = threadIdx.x, ty = threadIdx.y;   // (32,8)
  #pragma unroll
  for (int i=0;i<4;i++)
    tile[ty*4+i][tx] = inz[(size_t)(r0+ty*4+i)*C + c0 + tx];
  __syncthreads();
  #pragma unroll
  for (int i=0;i<4;i++)
    outz[(size_t)(c0+ty*4+i)*outStride + r0 + tx] = f2bf(tile[tx][ty*4+i]);
}

// ---------------- RoPE table (f32) ----------------
__global__ __launch_bounds__(256) void rope_tab(float* __restrict__ ctab,
                                                float* __restrict__ stab){
  int i = blockIdx.x*256 + threadIdx.x;   // S_LEN*64
  int p = i >> 6, j = i & 63;
  float freq = exp2f(-(float)j * (13.287712379549449f/64.0f));  // 10000^(-j/64)
  float a = (float)p * freq;
  ctab[i] = cosf(a);
  stab[i] = sinf(a);
}

// ---------------- GEMM: A[4096][2048] x BT[2048][2048] bf16, counted-vmcnt pipeline ------
// 256x128 tile, BK=64, 8 waves (4Mx2N, 64x64 each), ring-6 half-slots (144KB LDS),
// prefetch depth 2 K-tiles, vmcnt(9) (never 0 in-loop), 2 phases x 16 MFMA, 2 barriers/K-tile,
// both-sides (row&7)<<4 swizzle. grid: 1D 256 blocks x 512 thr, XCD swizzle.
// mode 0: out bf16 plain (B,H,S,F) | mode 1: V fragment-linear (16x1KB frags per kv-tile) |
// mode 2: f32+bias
__global__ __launch_bounds__(512) void gemm_bt(const u16* __restrict__ A,
                                               const u16* __restrict__ BT,
                                               const float* __restrict__ bias,
                                               void* __restrict__ out, int mode){
  const int K = 2048;
  const int NT = 32;                       // K/64
  __shared__ u16 lds[6*12288];             // 6 slots x 24KB: A-half [128][64] + B-half [64][64]
  const int t = threadIdx.x, w = t >> 6, l = t & 63;
  const int lr = l & 15, lg = l >> 4;
  const int wr = w >> 1, wc = w & 1;       // 4M x 2N waves, 64x64 output each
  int bid = blockIdx.x;
  int swz = (bid & 7)*32 + (bid >> 3);     // 256 % 8 == 0, bijective
  const int M0 = (swz >> 4) * 256, N0 = (swz & 15) * 128;

  f32x4 acc[4][4];
  #pragma unroll
  for (int i=0;i<4;i++)
    #pragma unroll
    for (int j=0;j<4;j++) acc[i][j] = f32x4{0.f,0.f,0.f,0.f};

  // stage half-tile h of (unwrapped) K-tile index ttu; slot from unwrapped index.
  auto stageH = [&](int ttu, int h){
    int slot = (2*ttu + h) % 6;
    int tt   = ttu & 31;
    char* base = (char*)&lds[slot*12288];
    #pragma unroll
    for (int j=0;j<2;j++){                       // A-half: 128 rows x 128B
      int d = w*2048 + j*1024 + l*16;
      int row = d >> 7;                          // 0..127
      int koff = ((l&7)*16) ^ ((row&7)<<4);
      gload16((const char*)A + ((size_t)(M0 + h*128 + row)*K + tt*64)*2 + koff,
              base + w*2048 + j*1024);
    }
    {                                            // B-half: 64 rows x 128B
      int d = w*1024 + l*16;
      int row = d >> 7;                          // 0..63
      int koff = ((l&7)*16) ^ ((row&7)<<4);
      gload16((const char*)BT + ((size_t)(N0 + h*64 + row)*K + tt*64)*2 + koff,
              base + 16384 + w*1024);
    }
  };

  // prologue: 2 K-tiles in flight (12 loads/wave), slots 0..3
  stageH(0,0); stageH(0,1); stageH(1,0); stageH(1,1);

  for (int kt=0; kt<NT; kt++){
    const char* Ab = (const char*)&lds[((2*kt + (wr>>1)) % 6)*12288];
    const char* Bb = (const char*)&lds[((2*kt + wc) % 6)*12288] + 16384;

    // ---- P0: issue H(t+2,0); counted wait; barrier; af + bf(nj0,1); 16 MFMA ----
    stageH(kt+2, 0);
    asm volatile("s_waitcnt vmcnt(9)" ::: "memory");   // tile kt fully landed
    __builtin_amdgcn_s_barrier();
    __builtin_amdgcn_sched_barrier(0);

    s8b af[4][2];
    #pragma unroll
    for (int mi=0;mi<4;mi++)
      #pragma unroll
      for (int kc=0;kc<2;kc++){
        int rA = (wr&1)*64 + mi*16 + lr;
        af[mi][kc] = *(const s8b*)(Ab + rA*128 + ((kc*64 + lg*16) ^ ((rA&7)<<4)));
      }
    {
      s8b bf[2][2];
      #pragma unroll
      for (int nj=0;nj<2;nj++){
        int rB = nj*16 + lr;
        bf[nj][0] = *(const s8b*)(Bb + rB*128 + ((0*64 + lg*16) ^ ((rB&7)<<4)));
        bf[nj][1] = *(const s8b*)(Bb + rB*128 + ((1*64 + lg*16) ^ ((rB&7)<<4)));
      }
      __builtin_amdgcn_s_setprio(1);
      #pragma unroll
      for (int mi=0;mi<4;mi++)
        #pragma unroll
        for (int nj=0;nj<2;nj++){
          acc[mi][nj] = mfma16(af[mi][0], bf[nj][0], acc[mi][nj]);
          acc[mi][nj] = mfma16(af[mi][1], bf[nj][1], acc[mi][nj]);
        }
      __builtin_amdgcn_s_setprio(0);
    }
    // ---- P1: issue H(t+2,1); bf(nj2,3); 16 MFMA; end barrier ----
    stageH(kt+2, 1);
    {
      s8b bf[2][2];
      #pragma unroll
      for (int nj=0;nj<2;nj++){
        int rB = (nj+2)*16 + lr;
        bf[nj][0] = *(const s8b*)(Bb + rB*128 + ((0*64 + lg*16) ^ ((rB&7)<<4)));
        bf[nj][1] = *(const s8b*)(Bb + rB*128 + ((1*64 + lg*16) ^ ((rB&7)<<4)));
      }
      __builtin_amdgcn_s_setprio(1);
      #pragma unroll
      for (int mi=0;mi<4;mi++)
        #pragma unroll
        for (int nj=0;nj<2;nj++){
          acc[mi][nj+2] = mfma16(af[mi][0], bf[nj][0], acc[mi][nj+2]);
          acc[mi][nj+2] = mfma16(af[mi][1], bf[nj][1], acc[mi][nj+2]);
        }
      __builtin_amdgcn_s_setprio(0);
    }
    __builtin_amdgcn_sched_barrier(0);
    __builtin_amdgcn_s_barrier();
    __builtin_amdgcn_sched_barrier(0);
  }
  asm volatile("s_waitcnt vmcnt(0)" ::: "memory");   // drain wrap-stages

  // epilogue: D layout col=lane&15, row=(lane>>4)*4+reg
  #pragma unroll
  for (int mi=0;mi<4;mi++){
    int growb = M0 + wr*64 + mi*16 + lg*4;
    #pragma unroll
    for (int nj=0;nj<4;nj++){
      int gcol = N0 + wc*64 + nj*16 + lr;
      float bv = bias[gcol];
      #pragma unroll
      for (int r=0;r<4;r++){
        int grow = growb + r;
        float v = acc[mi][nj][r] + bv;
        if (mode == 2){
          ((float*)out)[(size_t)grow*2048 + gcol] = v;
        } else {
          int b = grow >> 11, p = grow & 2047;
          int h = gcol >> 7,  f = gcol & 127;
          if (mode == 0){
            ((u16*)out)[(((size_t)(b*NHEAD+h))*S_LEN + p)*HD + f] = f2bf(v);
          } else {
            // V fragment-linear: 16 frags x 1KB per kv-tile; sigma-permute folded in.
            size_t base = ((size_t)(b*NHEAD+h)*PLANE_ELEMS)*2 + (size_t)(p>>6)*16384;
            int p6 = p & 63;
            int q_ = ((p6&12)<<1) | (p6&3) | ((p6&16)>>2);
            int kvp = (p6 & 32) | q_;
            int kc = kvp >> 5, lgv = (kvp >> 3) & 3, jv = kvp & 7;
            int off = (kc*8 + (f>>4))*1024 + (lgv*16 + (f&15))*16 + jv*2;
            *(u16*)((char*)out + base + off) = f2bf(v);
          }
        }
      }
    }
  }
}

// ---------------- RMSNorm + RoPE: q-path and k-path fused in one launch (blockIdx.y) -----
__global__ __launch_bounds__(256) void norm_rope2(const u16* __restrict__ qin,
                                                  u16* __restrict__ qout,
                                                  const float* __restrict__ qwv,
                                                  const u16* __restrict__ kin,
                                                  u16* __restrict__ kout,
                                                  const float* __restrict__ kwv,
                                                  const float* __restrict__ ctab,
                                                  const float* __restrict__ stab,
                                                  float qscale){
  int t = threadIdx.x, w = t>>6, l = t&63;
  int isK = blockIdx.y;
  const u16* in  = isK ? kin  : qin;
  u16*       outp= isK ? kout : qout;
  const float* nw= isK ? kwv  : qwv;
  float oscale   = isK ? 1.0f : qscale;
  size_t R = (size_t)blockIdx.x*4 + w;     // over B*H*S rows
  int p = (int)(R & (S_LEN-1));
  size_t base = R * HD;
  float x0 = bf2f(in[base + l]);
  float x1 = bf2f(in[base + 64 + l]);
  float ss = x0*x0 + x1*x1;
  #pragma unroll
  for (int m=1;m<64;m<<=1) ss += __shfl_xor(ss, m);
  float rms = sqrtf(ss * (1.0f/128.0f));
  float sc = oscale / (rms + 1e-6f);
  float xn0 = x0 * sc * nw[l];
  float xn1 = x1 * sc * nw[64+l];
  float c = ctab[(size_t)p*64 + l], s = stab[(size_t)p*64 + l];
  float o0 = xn0*c - xn1*s;
  float o1 = xn1*c + xn0*s;
  if (!isK){
    outp[base + l]      = f2bf(o0);
    outp[base + 64 + l] = f2bf(o1);
  } else {
    size_t plane = R >> 11;
    int kv = p & 63;
    size_t tb = (plane*(size_t)PLANE_ELEMS + (size_t)(p>>6)*8192) * 2;
    int b0 = (kv*256 + l*2)        ^ ((kv&7)<<4);
    int b1 = (kv*256 + (64+l)*2)   ^ ((kv&7)<<4);
    *(u16*)((char*)outp + tb + b0) = f2bf(o0);
    *(u16*)((char*)outp + tb + b1) = f2bf(o1);
  }
}

// ---------------- flash attention: 4 waves, QBLK=128 (32 rows/wave), 2 KV-tiles/barrier ---
// K LDS ring-4 (64KB); V global->register (fragment-linear); no-max softmax (bounded);
// denominator via ones-MFMA. One __syncthreads per 128 kv.
__global__ __launch_bounds__(256,2) void attn_fwd(const u16* __restrict__ qn, // prescaled ATT_SCALE*LOG2E
                                                  const u16* __restrict__ kn, // tiled swizzled
                                                  const u16* __restrict__ vt, // V fragment-linear
                                                  u16* __restrict__ attn_out){// (B,S,H,F)
  __shared__ u16 Klds[4][8192];     // ring-4: [64 kv][128 f] swizzled, 64KB
  int t = threadIdx.x, w = t>>6, l = t&63;
  int lr = l&15, lg = l>>4;

  int bid = blockIdx.x;                  // 0..511
  int xcd = bid & 7, j = bid >> 3;       // j 0..63
  int plane = xcd*4 + (j >> 4);          // 4 planes per XCD
  int qb = j & 15;
  int q0 = qb*128 + w*32;                // 32 q-rows per wave

  const s8b ones = { (short)0x3F80, (short)0x3F80, (short)0x3F80, (short)0x3F80,
                     (short)0x3F80, (short)0x3F80, (short)0x3F80, (short)0x3F80 };

  s8b qf[2][4];
  #pragma unroll
  for (int qi=0; qi<2; qi++)
    #pragma unroll
    for (int fc=0; fc<4; fc++)
      qf[qi][fc] = *(const s8b*)(qn + ((size_t)plane*S_LEN + q0 + qi*16 + lr)*HD + fc*32 + lg*8);

  f32x4 lacc[2];                         // denominators, rows q = lg*4+r (same map as oacc)
  lacc[0] = f32x4{0.f,0.f,0.f,0.f};
  lacc[1] = f32x4{0.f,0.f,0.f,0.f};
  f32x4 oacc[2][8];
  #pragma unroll
  for (int qi=0;qi<2;qi++)
    #pragma unroll
    for (int i=0;i<8;i++) oacc[qi][i] = f32x4{0.f,0.f,0.f,0.f};

  const u16* kbase = kn + (size_t)plane*PLANE_ELEMS;
  const char* vbase = (const char*)vt + (size_t)plane*PLANE_ELEMS*2;

  auto stage = [&](int buf, int kt){     // K only: 4 gloads/wave
    #pragma unroll
    for (int i=0;i<4;i++)
      gload16(kbase + (size_t)kt*8192 + w*2048 + i*512 + l*8, &Klds[buf][w*2048 + i*512]);
  };

  // one tile: QK^T (K from Klds[buf]) -> exp2 -> pack -> PV (V from global regs)
  auto tile = [&](int buf, int kt){
    const char* vb = vbase + (size_t)kt*16384;
    s8b vf0[8];
    #pragma unroll
    for (int fc2=0; fc2<8; fc2++)
      vf0[fc2] = *(const s8b*)(vb + fc2*1024 + l*16);

    f32x4 sacc[4][2];
    #pragma unroll
    for (int c=0;c<4;c++){
      sacc[c][0] = f32x4{0.f,0.f,0.f,0.f};
      sacc[c][1] = f32x4{0.f,0.f,0.f,0.f};
    }
    __builtin_amdgcn_s_setprio(1);
    #pragma unroll
    for (int c=0;c<4;c++){
      int kv = c*16 + lr;
      #pragma unroll
      for (int fc=0; fc<4; fc++){
        int byte = (kv*256 + (fc*32 + lg*8)*2) ^ ((kv&7)<<4);
        s8b kf = *(const s8b*)((const char*)&Klds[buf][0] + byte);
        sacc[c][0] = mfma16(kf, qf[0][fc], sacc[c][0]);
        sacc[c][1] = mfma16(kf, qf[1][fc], sacc[c][1]);
      }
    }
    __builtin_amdgcn_s_setprio(0);

    s8b vf1[8];
    #pragma unroll
    for (int fc2=0; fc2<8; fc2++)
      vf1[fc2] = *(const s8b*)(vb + (8+fc2)*1024 + l*16);

    float pv[2][4][4];
    #pragma unroll
    for (int qi=0;qi<2;qi++)
      #pragma unroll
      for (int c=0;c<4;c++){
        pv[qi][c][0] = exp2f(sacc[c][qi][0]);
        pv[qi][c][1] = exp2f(sacc[c][qi][1]);
        pv[qi][c][2] = exp2f(sacc[c][qi][2]);
        pv[qi][c][3] = exp2f(sacc[c][qi][3]);
      }

    s8b pa[2][2];
    #pragma unroll
    for (int qi=0;qi<2;qi++)
      #pragma unroll
      for (int kc=0;kc<2;kc++){
        union { s8b v; unsigned u[4]; } pu;
        pu.u[0] = cvtpk(pv[qi][2*kc][0],   pv[qi][2*kc][1]);
        pu.u[1] = cvtpk(pv[qi][2*kc][2],   pv[qi][2*kc][3]);
        pu.u[2] = cvtpk(pv[qi][2*kc+1][0], pv[qi][2*kc+1][1]);
        pu.u[3] = cvtpk(pv[qi][2*kc+1][2], pv[qi][2*kc+1][3]);
        pa[qi][kc] = pu.v;
      }

    __builtin_amdgcn_s_setprio(1);
    lacc[0] = mfma16(pa[0][0], ones, lacc[0]);
    lacc[1] = mfma16(pa[1][0], ones, lacc[1]);
    #pragma unroll
    for (int fc2=0; fc2<8; fc2++){
      oacc[0][fc2] = mfma16(pa[0][0], vf0[fc2], oacc[0][fc2]);
      oacc[1][fc2] = mfma16(pa[1][0], vf0[fc2], oacc[1][fc2]);
    }
    lacc[0] = mfma16(pa[0][1], ones, lacc[0]);
    lacc[1] = mfma16(pa[1][1], ones, lacc[1]);
    #pragma unroll
    for (int fc2=0; fc2<8; fc2++){
      oacc[0][fc2] = mfma16(pa[0][1], vf1[fc2], oacc[0][fc2]);
      oacc[1][fc2] = mfma16(pa[1][1], vf1[fc2], oacc[1][fc2]);
    }
    __builtin_amdgcn_s_setprio(0);
  };

  stage(0, 0); stage(1, 1);              // tiles 0,1 -> bufs 0,1
  for (int it=0; it<16; it++){
    __syncthreads();                     // bufs (2it)&3,(2it+1)&3 staged; other two free
    int b0 = (2*it) & 3, b1 = (2*it+1) & 3;
    if (it < 15){
      stage((2*it+2)&3, 2*it+2);         // into the two bufs read last iteration
      stage((2*it+3)&3, 2*it+3);
    }
    tile(b0, 2*it);
    tile(b1, 2*it+1);
  }

  // epilogue: in-lane normalize (lacc rows == oacc rows), no shfl
  int b = plane >> 4, h = plane & 15;
  #pragma unroll
  for (int qi=0;qi<2;qi++){
    float inv[4];
    #pragma unroll
    for (int r=0;r<4;r++) inv[r] = 1.0f / lacc[qi][r];
    #pragma unroll
    for (int fc2=0; fc2<8; fc2++){
      int f = fc2*16 + lr;
      #pragma unroll
      for (int r=0;r<4;r++){
        int row = q0 + qi*16 + lg*4 + r;
        float o = oacc[qi][fc2][r] * inv[r];
        attn_out[(((size_t)b*S_LEN + row)*NHEAD + h)*HD + f] = f2bf(o);
      }
    }
  }
}

// ---------------------------------------------------------------------------
extern "C" void kernel_launch(void* const* d_in, const int* in_sizes, int n_in,
                              void* d_out, int out_size, void* d_ws, size_t ws_size,
                              hipStream_t stream){
  const float* xq = (const float*)d_in[0];
  const float* xk = (const float*)d_in[1];
  const float* xv = (const float*)d_in[2];
  const float* WQ = (const float*)d_in[3];
  const float* WK = (const float*)d_in[4];
  const float* WV = (const float*)d_in[5];
  const float* WO = (const float*)d_in[6];
  const float* bQ = (const float*)d_in[7];
  const float* bK = (const float*)d_in[8];
  const float* bV = (const float*)d_in[9];
  const float* bO = (const float*)d_in[10];
  const float* qw = (const float*)d_in[11];
  const float* kw = (const float*)d_in[12];

  char* ws = (char*)d_ws;
  size_t off = 0;
  auto alloc = [&](size_t bytes)->void*{
    void* p = ws + off; off += (bytes + 255) & ~(size_t)255; return p;
  };
  const size_t ACT = (size_t)ROWS*DM*2;    // 16.78 MB (bf16 [4096][2048])
  const size_t WMT = (size_t)DM*DM*2;      // 8.39 MB
  u16* xqb  = (u16*)alloc(ACT);
  u16* xkb  = (u16*)alloc(ACT);
  u16* xvb  = (u16*)alloc(ACT);
  u16* WqT  = (u16*)alloc(WMT);
  u16* WkT  = (u16*)alloc(WMT);
  u16* WvT  = (u16*)alloc(WMT);
  u16* WoT  = (u16*)alloc(WMT);
  u16* qraw = (u16*)alloc(ACT);
  u16* kraw = (u16*)alloc(ACT);
  u16* knT  = (u16*)alloc(ACT);
  u16* vtS  = (u16*)alloc(ACT);
  u16* attn = (u16*)alloc(ACT);
  float* ctab = (float*)alloc((size_t)S_LEN*64*4);
  float* stab = (float*)alloc((size_t)S_LEN*64*4);
  if (off > ws_size) return;               // ws too small -> absmax will flag it

  const int n4 = ROWS*DM/4;                // 2097152
  cvt4x3<<<dim3(n4/256, 3), dim3(256), 0, stream>>>((const float4*)xq, (const float4*)xk,
                                                    (const float4*)xv, (uint2*)xqb,
                                                    (uint2*)xkb, (uint2*)xvb, n4);
  rope_tab<<<dim3(S_LEN*64/256), dim3(256), 0, stream>>>(ctab, stab);
  // W_Q/K/V: (H,D,F) -> [h*128+f][d]
  transpose_cvt<<<dim3(64,4,16), dim3(32,8), 0, stream>>>(WQ, WqT, 2048, 128, 2048);
  transpose_cvt<<<dim3(64,4,16), dim3(32,8), 0, stream>>>(WK, WkT, 2048, 128, 2048);
  transpose_cvt<<<dim3(64,4,16), dim3(32,8), 0, stream>>>(WV, WvT, 2048, 128, 2048);
  // W_O: [hf][m] -> [m][hf]
  transpose_cvt<<<dim3(64,64,1), dim3(32,8), 0, stream>>>(WO, WoT, 2048, 2048, 2048);

  gemm_bt<<<dim3(256), dim3(512), 0, stream>>>(xqb, WqT, bQ, qraw, 0);
  gemm_bt<<<dim3(256), dim3(512), 0, stream>>>(xkb, WkT, bK, kraw, 0);
  gemm_bt<<<dim3(256), dim3(512), 0, stream>>>(xvb, WvT, bV, vtS, 1);

  norm_rope2<<<dim3(NPLANE*S_LEN/4, 2), dim3(256), 0, stream>>>(qraw, qraw, qw,
                                                                kraw, knT, kw,
                                                                ctab, stab, ATT_SCALE*LOG2E);

  attn_fwd<<<dim3(512), dim3(256), 0, stream>>>(qraw, knT, vtS, attn);

  gemm_bt<<<dim3(256), dim3(512), 0, stream>>>(attn, WoT, bO, d_out, 2);
}